// Round 7
// baseline (1152.888 us; speedup 1.0000x reference)
//
#include <hip/hip_runtime.h>

#define TT 100
#define BB 2048
#define NI 3
#define NU 128
#define NB 256
#define NPC 256
#define NHD 12

typedef __attribute__((ext_vector_type(8))) short short8;
typedef __attribute__((ext_vector_type(4))) float f32x4;

// gru LDS: 120 x 1KB fragments | 4 x 4KB planes | xt[2][16][4] f32
#define GRU_FRAG_BYTES (120 * 1024)
#define GRU_PLANES_OFF GRU_FRAG_BYTES
#define GRU_XT_OFF (GRU_FRAG_BYTES + 16 * 1024)
#define GRU_LDS_BYTES (GRU_XT_OFF + 2 * 16 * 4 * 4)

__device__ __forceinline__ float fast_sigmoid(float x) {
  return 1.0f / (1.0f + __expf(-x));
}
__device__ __forceinline__ float fast_tanh(float x) {
  return 1.0f - 2.0f / (__expf(2.0f * x) + 1.0f);
}
__device__ __forceinline__ short f2bf(float f) {
  uint32_t u = __float_as_uint(f);
  u += 0x7FFF + ((u >> 16) & 1);  // RNE
  return (short)(u >> 16);
}
__device__ __forceinline__ float bf2f(short s) {
  return __uint_as_float(((uint32_t)(uint16_t)s) << 16);
}

// ---------------------------------------------------------------------------
// h0 = concat(init_pc, init_hd) @ W_embed + b_embed     [B, NU]
// ---------------------------------------------------------------------------
__global__ __launch_bounds__(256) void embed_kernel(
    const float* __restrict__ init_pc, const float* __restrict__ init_hd,
    const float* __restrict__ W_embed, const float* __restrict__ b_embed,
    float* __restrict__ h0) {
  __shared__ float pcs[2][NPC];
  __shared__ float hds[2][NHD];
  const int tid = threadIdx.x;
  const int b0 = blockIdx.x * 2;

  for (int idx = tid; idx < 2 * NPC; idx += 256)
    pcs[idx >> 8][idx & 255] =
        init_pc[(size_t)(b0 + (idx >> 8)) * NPC + (idx & 255)];
  if (tid < 2 * NHD) {
    int rr = tid / NHD, cc = tid - rr * NHD;
    hds[rr][cc] = init_hd[(size_t)(b0 + rr) * NHD + cc];
  }
  __syncthreads();

  const int half = tid >> 7;
  const int j = tid & 127;
  const float* Wp = W_embed + j;
  float a0 = 0.f, a1 = 0.f, a2 = 0.f, a3 = 0.f;
#pragma unroll 4
  for (int k = 0; k < NPC; k += 4) {
    a0 = fmaf(pcs[half][k + 0], Wp[(k + 0) * NU], a0);
    a1 = fmaf(pcs[half][k + 1], Wp[(k + 1) * NU], a1);
    a2 = fmaf(pcs[half][k + 2], Wp[(k + 2) * NU], a2);
    a3 = fmaf(pcs[half][k + 3], Wp[(k + 3) * NU], a3);
  }
#pragma unroll
  for (int k = 0; k < NHD; ++k)
    a0 = fmaf(hds[half][k], Wp[(NPC + k) * NU], a0);
  float acc = b_embed[j] + ((a0 + a1) + (a2 + a3));
  h0[(size_t)(b0 + half) * NU + j] = acc;
}

// ---------------------------------------------------------------------------
// Pre-pack GRU weights as bf16 MFMA B-fragments into workspace.
// ws frag f (1KB = 64 lanes x short8):
//   f in [0,96):    hi of U_g, g=f>>5 (0=Uz,1=Ur,2=Uh), nt=(f>>2)&7, kt=f&3
//   f in [96,128):  lo of Uh, nt=(f>>2)&7, kt=f&3
//   f in [128,152): augmented x-proj frag: w=f-128, g=w>>3, nt=w&7,
//                   B[k][col]: k<3 -> W_g[k][col], k==3 -> bias_g[col], else 0
// ---------------------------------------------------------------------------
__global__ __launch_bounds__(256) void prepack_gru_kernel(
    const float* __restrict__ Uz, const float* __restrict__ Ur,
    const float* __restrict__ Uh, const float* __restrict__ Wz,
    const float* __restrict__ Wr, const float* __restrict__ Wh,
    const float* __restrict__ bz, const float* __restrict__ br,
    const float* __restrict__ bh, short* __restrict__ gfrags) {
  int t = blockIdx.x * 256 + threadIdx.x;
  if (t >= 152 * 64) return;
  const int f = t >> 6, lane = t & 63;
  const int ln15 = lane & 15, g4 = lane >> 4;
  short8 p;
  if (f < 128) {
    const int g = f >> 5;  // 3 for the Uh-lo band
    const int nt = (f >> 2) & 7, kt = f & 3;
    const float* U = (g == 0) ? Uz : (g == 1) ? Ur : Uh;
#pragma unroll
    for (int e = 0; e < 8; ++e) {
      const float v = U[(kt * 32 + g4 * 8 + e) * NU + nt * 16 + ln15];
      const short hi = f2bf(v);
      p[e] = (f < 96) ? hi : f2bf(v - bf2f(hi));
    }
  } else {
    const int w = f - 128;
    const int g = w >> 3, nt = w & 7;
    const float* W = (g == 0) ? Wz : (g == 1) ? Wr : Wh;
    const float* bb = (g == 0) ? bz : (g == 1) ? br : bh;
    const int col = nt * 16 + ln15;
#pragma unroll
    for (int e = 0; e < 8; ++e) {
      const int k = g4 * 8 + e;
      float v = 0.0f;
      if (k < 3) v = W[k * NU + col];
      if (k == 3) v = bb[col];
      p[e] = f2bf(v);
    }
  }
  *((short8*)gfrags + (f * 64 + lane)) = p;
}

// ---------------------------------------------------------------------------
// Barrier-free GRU scan. 128 blocks x ONE wave (64 thr); wave owns 16 batch
// rows x all 128 features -> recurrence never crosses waves, zero s_barrier.
// U hi + x-proj frags stream from LDS (120KB); Uh-lo lives in 128 VGPRs
// (3-term h-tilde); gates are 2-term. h master in D-layout regs; rh/h bounce
// through XOR-swizzled bf16 hi/lo LDS planes for the D->A transpose.
// ---------------------------------------------------------------------------
__global__ __launch_bounds__(64, 1) void gru_scan_kernel(
    const float* __restrict__ x, const float* __restrict__ h0,
    const short* __restrict__ gfrags, float* __restrict__ states,
    float* __restrict__ final_state) {
  extern __shared__ char smem[];
  const short8* fr = (const short8*)smem;
  char* h_hi = smem + GRU_PLANES_OFF;
  char* h_lo = h_hi + 4096;
  char* p_hi = h_lo + 4096;
  char* p_lo = p_hi + 4096;
  float* xt = (float*)(smem + GRU_XT_OFF);  // [2][16][4]

  const int lane = threadIdx.x;
  const int ln15 = lane & 15, g4 = lane >> 4;
  const int row0 = blockIdx.x * 16;

  // ---- stage 120 fragments into LDS (slots 0-95: U hi, 96-119: x-proj) ----
  {
    short8* dst = (short8*)smem;
    for (int i = lane; i < 120 * 64; i += 64) {
      const int slot = i >> 6;
      const int src = (slot < 96) ? slot : slot + 32;
      dst[i] = *(const short8*)(gfrags + ((size_t)src * 64 + (i & 63)) * 8);
    }
  }

  // ---- Uh lo fragments -> 128 VGPRs ----
  short8 Ulo[8][4];
#pragma unroll
  for (int nt = 0; nt < 8; ++nt)
#pragma unroll
    for (int kt = 0; kt < 4; ++kt)
      Ulo[nt][kt] =
          *(const short8*)(gfrags + ((size_t)(96 + nt * 4 + kt) * 64 + lane) * 8);

  // ---- A-fragment read offsets (same verified swizzle as heads) ----
  int foff[4];
#pragma unroll
  for (int kt = 0; kt < 4; ++kt)
    foff[kt] = ln15 * 256 + ((kt * 64 + g4 * 16) ^ ((ln15 & 7) << 4));

  // ---- init h (D-layout regs) + h planes ----
  float hreg[8][4];
#pragma unroll
  for (int nt = 0; nt < 8; ++nt)
#pragma unroll
    for (int q = 0; q < 4; ++q) {
      const int row = g4 * 4 + q;
      const float v = h0[(size_t)(row0 + row) * NU + nt * 16 + ln15];
      hreg[nt][q] = v;
      const int byte =
          row * 256 + (((nt * 16 + ln15) * 2) ^ ((row & 7) << 4));
      const short hi = f2bf(v);
      *(short*)(h_hi + byte) = hi;
      *(short*)(h_lo + byte) = f2bf(v - bf2f(hi));
    }

  // ---- xt[0] <- x[0] ----
  if (lane < 48) {
    const int r = lane / 3, i = lane - r * 3;
    xt[0 * 64 + r * 4 + i] = x[(size_t)(row0 + r) * NI + i];
  }

#pragma unroll 1
  for (int t = 0; t < TT; ++t) {
    const int pb = t & 1;

    // ---- h A-fragments + x fragment ----
    short8 ahi[4], alo[4];
#pragma unroll
    for (int kt = 0; kt < 4; ++kt) {
      ahi[kt] = *(const short8*)(h_hi + foff[kt]);
      alo[kt] = *(const short8*)(h_lo + foff[kt]);
    }
    short8 ax = {0, 0, 0, 0, 0, 0, 0, 0};
    {
      const float4 xv = *(const float4*)&xt[pb * 64 + ln15 * 4];
      if (g4 == 0) {
        ax[0] = f2bf(xv.x);
        ax[1] = f2bf(xv.y);
        ax[2] = f2bf(xv.z);
        ax[3] = (short)0x3F80;  // bf16 1.0 -> bias row
      }
    }
    // prefetch next x (fire early; consumed after phase B)
    float xnext = 0.0f;
    int xr = 0, xi = 0;
    if (t + 1 < TT && lane < 48) {
      xr = lane / 3;
      xi = lane - xr * 3;
      xnext = x[(size_t)((t + 1) * BB + row0 + xr) * NI + xi];
    }

    // ================= phase A: z and r (8 chains each) =================
    f32x4 zacc[8], racc[8];
#pragma unroll
    for (int nt = 0; nt < 8; ++nt) {
      const f32x4 zz = {0.f, 0.f, 0.f, 0.f};
      f32x4 z = __builtin_amdgcn_mfma_f32_16x16x32_bf16(
          ax, fr[(96 + nt) * 64 + lane], zz, 0, 0, 0);
      f32x4 r = __builtin_amdgcn_mfma_f32_16x16x32_bf16(
          ax, fr[(104 + nt) * 64 + lane], zz, 0, 0, 0);
      const short8* Bz = fr + (0 * 32 + nt * 4) * 64 + lane;
      const short8* Br = fr + (1 * 32 + nt * 4) * 64 + lane;
#pragma unroll
      for (int kt = 0; kt < 4; ++kt) {
        const short8 b_z = Bz[kt * 64];
        const short8 b_r = Br[kt * 64];
        z = __builtin_amdgcn_mfma_f32_16x16x32_bf16(ahi[kt], b_z, z, 0, 0, 0);
        r = __builtin_amdgcn_mfma_f32_16x16x32_bf16(ahi[kt], b_r, r, 0, 0, 0);
        z = __builtin_amdgcn_mfma_f32_16x16x32_bf16(alo[kt], b_z, z, 0, 0, 0);
        r = __builtin_amdgcn_mfma_f32_16x16x32_bf16(alo[kt], b_r, r, 0, 0, 0);
      }
      zacc[nt] = z;
      racc[nt] = r;
    }

    // ---- sigmoid, rh -> p planes; zacc becomes the z gate ----
#pragma unroll
    for (int nt = 0; nt < 8; ++nt)
#pragma unroll
      for (int q = 0; q < 4; ++q) {
        const int row = g4 * 4 + q;
        const float rh = fast_sigmoid(racc[nt][q]) * hreg[nt][q];
        const short hi = f2bf(rh);
        const int byte =
            row * 256 + (((nt * 16 + ln15) * 2) ^ ((row & 7) << 4));
        *(short*)(p_hi + byte) = hi;
        *(short*)(p_lo + byte) = f2bf(rh - bf2f(hi));
        zacc[nt][q] = fast_sigmoid(zacc[nt][q]);
      }

    // ================= phase B: h-tilde (3-term) + update =================
    short8 phi[4], plo[4];
#pragma unroll
    for (int kt = 0; kt < 4; ++kt) {
      phi[kt] = *(const short8*)(p_hi + foff[kt]);
      plo[kt] = *(const short8*)(p_lo + foff[kt]);
    }
#pragma unroll
    for (int nt = 0; nt < 8; ++nt) {
      const f32x4 zz = {0.f, 0.f, 0.f, 0.f};
      f32x4 h = __builtin_amdgcn_mfma_f32_16x16x32_bf16(
          ax, fr[(112 + nt) * 64 + lane], zz, 0, 0, 0);
      const short8* Bh = fr + (2 * 32 + nt * 4) * 64 + lane;
#pragma unroll
      for (int kt = 0; kt < 4; ++kt) {
        const short8 b_h = Bh[kt * 64];
        h = __builtin_amdgcn_mfma_f32_16x16x32_bf16(phi[kt], b_h, h, 0, 0, 0);
        h = __builtin_amdgcn_mfma_f32_16x16x32_bf16(plo[kt], b_h, h, 0, 0, 0);
        h = __builtin_amdgcn_mfma_f32_16x16x32_bf16(phi[kt], Ulo[nt][kt], h, 0,
                                                    0, 0);
      }
      // update 4 elements, write h planes + states (fire-and-forget)
#pragma unroll
      for (int q = 0; q < 4; ++q) {
        const int row = g4 * 4 + q;
        const float htw = fast_tanh(h[q]);
        const float hnew = fmaf(zacc[nt][q], htw - hreg[nt][q], hreg[nt][q]);
        hreg[nt][q] = hnew;
        const int byte =
            row * 256 + (((nt * 16 + ln15) * 2) ^ ((row & 7) << 4));
        const short hi = f2bf(hnew);
        *(short*)(h_hi + byte) = hi;
        *(short*)(h_lo + byte) = f2bf(hnew - bf2f(hi));
        states[((size_t)t * BB + row0 + row) * NU + nt * 16 + ln15] = hnew;
      }
    }

    // ---- stage next x ----
    if (t + 1 < TT && lane < 48) xt[(pb ^ 1) * 64 + xr * 4 + xi] = xnext;
  }

#pragma unroll
  for (int nt = 0; nt < 8; ++nt)
#pragma unroll
    for (int q = 0; q < 4; ++q)
      final_state[(size_t)(row0 + g4 * 4 + q) * NU + nt * 16 + ln15] =
          hreg[nt][q];
}

// ---------------------------------------------------------------------------
// Pre-pack heads weights into bf16 MFMA B-fragment order (unchanged).
// ---------------------------------------------------------------------------
__global__ __launch_bounds__(256) void prepack_kernel(
    const float* __restrict__ Wb, const float* __restrict__ Wpc,
    const float* __restrict__ Whd, short* __restrict__ Wb_pack,
    short* __restrict__ Wpc_pack, short* __restrict__ Whd_pack) {
  int t = blockIdx.x * 256 + threadIdx.x;
  if (t >= 200 * 64) return;
  int fb = t >> 6, lane = t & 63;
  const float* W;
  short* out;
  int n_tile, k_tile, N, local;
  if (fb < 64) {
    W = Wb; out = Wb_pack; local = fb; n_tile = fb >> 2; k_tile = fb & 3; N = 256;
  } else if (fb < 192) {
    int f = fb - 64;
    W = Wpc; out = Wpc_pack; local = f; n_tile = f >> 3; k_tile = f & 7; N = 256;
  } else {
    int f = fb - 192;
    W = Whd; out = Whd_pack; local = f; n_tile = 0; k_tile = f; N = 12;
  }
  short8 p;
#pragma unroll
  for (int e = 0; e < 8; ++e) {
    int k = k_tile * 32 + (lane >> 4) * 8 + e;
    int colc = n_tile * 16 + (lane & 15);
    float v = (colc < N) ? W[k * N + colc] : 0.0f;
    p[e] = f2bf(v);
  }
  *((short8*)out + (local * 64 + lane)) = p;
}

// ---------------------------------------------------------------------------
// MFMA heads: 64 rows/block, 256 threads (4 waves, 16-row stripe each).
// ---------------------------------------------------------------------------
__global__ __launch_bounds__(256, 3) void heads_mfma_kernel(
    const float* __restrict__ states, const short* __restrict__ Wb_pack,
    const short* __restrict__ Wpc_pack, const short* __restrict__ Whd_pack,
    const float* __restrict__ b_pc, const float* __restrict__ b_hd,
    float* __restrict__ out_hd, float* __restrict__ out_pc,
    float* __restrict__ out_bn) {
  __shared__ short s_lds[64 * 128];   // 16 KB
  __shared__ short bn_lds[64 * 256];  // 32 KB
  const int tid = threadIdx.x;
  const size_t R0 = (size_t)blockIdx.x * 64;

  for (int c = tid; c < 1024; c += 256) {
    int row = c >> 4, s16 = c & 15;
    const float* src = states + (R0 + row) * 128 + s16 * 8;
    float4 v0 = *(const float4*)src;
    float4 v1 = *(const float4*)(src + 4);
    short8 p;
    p[0] = f2bf(v0.x); p[1] = f2bf(v0.y); p[2] = f2bf(v0.z); p[3] = f2bf(v0.w);
    p[4] = f2bf(v1.x); p[5] = f2bf(v1.y); p[6] = f2bf(v1.z); p[7] = f2bf(v1.w);
    int byte = row * 256 + ((s16 * 16) ^ ((row & 7) << 4));
    *(short8*)((char*)s_lds + byte) = p;
  }
  __syncthreads();

  const int lane = tid & 63;
  const int wave = tid >> 6;
  const int ln15 = lane & 15;
  const int ln4 = lane >> 4;
  const int r0 = wave * 16;

  {
    short8 a[4];
#pragma unroll
    for (int kt = 0; kt < 4; ++kt) {
      int byte =
          (r0 + ln15) * 256 + ((kt * 64 + ln4 * 16) ^ ((ln15 & 7) << 4));
      a[kt] = *(const short8*)((const char*)s_lds + byte);
    }
#pragma unroll
    for (int nt = 0; nt < 16; ++nt) {
      f32x4 acc = {0.f, 0.f, 0.f, 0.f};
      const short8* bp = (const short8*)Wb_pack + (nt * 4) * 64 + lane;
#pragma unroll
      for (int kt = 0; kt < 4; ++kt)
        acc = __builtin_amdgcn_mfma_f32_16x16x32_bf16(a[kt], bp[kt * 64], acc,
                                                      0, 0, 0);
      int colc = nt * 16 + ln15;
#pragma unroll
      for (int q = 0; q < 4; ++q) {
        int row = r0 + ln4 * 4 + q;
        out_bn[(R0 + row) * NB + colc] = acc[q];
        int byte = row * 512 + ((colc * 2) ^ ((row & 7) << 4));
        *(short*)((char*)bn_lds + byte) = f2bf(acc[q]);
      }
    }
  }
  __syncthreads();

  {
    short8 ab[8];
#pragma unroll
    for (int kt = 0; kt < 8; ++kt) {
      int byte =
          (r0 + ln15) * 512 + ((kt * 64 + ln4 * 16) ^ ((ln15 & 7) << 4));
      ab[kt] = *(const short8*)((const char*)bn_lds + byte);
    }
#pragma unroll
    for (int nt = 0; nt < 16; ++nt) {
      int colc = nt * 16 + ln15;
      float bias = b_pc[colc];
      f32x4 acc = {bias, bias, bias, bias};
      const short8* bp = (const short8*)Wpc_pack + (nt * 8) * 64 + lane;
#pragma unroll
      for (int kt = 0; kt < 8; ++kt)
        acc = __builtin_amdgcn_mfma_f32_16x16x32_bf16(ab[kt], bp[kt * 64], acc,
                                                      0, 0, 0);
#pragma unroll
      for (int q = 0; q < 4; ++q)
        out_pc[(R0 + r0 + ln4 * 4 + q) * NPC + colc] = acc[q];
    }
    {
      int colc = ln15;
      float bias = (colc < NHD) ? b_hd[colc] : 0.0f;
      f32x4 acc = {bias, bias, bias, bias};
      const short8* bp = (const short8*)Whd_pack + lane;
#pragma unroll
      for (int kt = 0; kt < 8; ++kt)
        acc = __builtin_amdgcn_mfma_f32_16x16x32_bf16(ab[kt], bp[kt * 64], acc,
                                                      0, 0, 0);
      if (colc < NHD) {
#pragma unroll
        for (int q = 0; q < 4; ++q)
          out_hd[(R0 + r0 + ln4 * 4 + q) * NHD + colc] = acc[q];
      }
    }
  }
}

// ---------------------------------------------------------------------------
extern "C" void kernel_launch(void* const* d_in, const int* in_sizes, int n_in,
                              void* d_out, int out_size, void* d_ws,
                              size_t ws_size, hipStream_t stream) {
  (void)in_sizes;
  (void)n_in;
  (void)out_size;
  (void)ws_size;
  const float* x = (const float*)d_in[0];
  const float* init_pc = (const float*)d_in[1];
  const float* init_hd = (const float*)d_in[2];
  const float* Wz = (const float*)d_in[3];
  const float* Wr = (const float*)d_in[4];
  const float* Wh = (const float*)d_in[5];
  const float* Uz = (const float*)d_in[6];
  const float* Ur = (const float*)d_in[7];
  const float* Uh = (const float*)d_in[8];
  const float* bz = (const float*)d_in[9];
  const float* br = (const float*)d_in[10];
  const float* bh = (const float*)d_in[11];
  const float* W_embed = (const float*)d_in[12];
  const float* b_embed = (const float*)d_in[13];
  const float* W_bneck = (const float*)d_in[14];
  const float* W_pc = (const float*)d_in[15];
  const float* b_pc = (const float*)d_in[16];
  const float* W_hd = (const float*)d_in[17];
  const float* b_hd = (const float*)d_in[18];

  float* out = (float*)d_out;
  float* out_hd = out;
  float* out_pc = out_hd + (size_t)TT * BB * NHD;
  float* out_bn = out_pc + (size_t)TT * BB * NPC;
  float* out_st = out_bn + (size_t)TT * BB * NB;
  float* out_fs = out_st + (size_t)TT * BB * NU;

  float* h0 = (float*)d_ws;                            // 1 MB
  short* Wb_pack = (short*)((char*)d_ws + (1 << 20));  // 64 KB
  short* Wpc_pack = Wb_pack + 64 * 64 * 8;             // 128 KB
  short* Whd_pack = Wpc_pack + 128 * 64 * 8;           // 8 KB
  short* gru_frags = (short*)((char*)d_ws + (1 << 20) + 200 * 1024);  // 152 KB

  // allow 139.7 KB dynamic LDS for the scan kernel (idempotent host call)
  hipFuncSetAttribute((const void*)gru_scan_kernel,
                      hipFuncAttributeMaxDynamicSharedMemorySize,
                      GRU_LDS_BYTES);

  prepack_kernel<<<50, 256, 0, stream>>>(W_bneck, W_pc, W_hd, Wb_pack,
                                         Wpc_pack, Whd_pack);
  prepack_gru_kernel<<<38, 256, 0, stream>>>(Uz, Ur, Uh, Wz, Wr, Wh, bz, br,
                                             bh, gru_frags);
  embed_kernel<<<BB / 2, 256, 0, stream>>>(init_pc, init_hd, W_embed, b_embed,
                                           h0);
  gru_scan_kernel<<<BB / 16, 64, GRU_LDS_BYTES, stream>>>(x, h0, gru_frags,
                                                          out_st, out_fs);
  heads_mfma_kernel<<<(TT * BB) / 64, 256, 0, stream>>>(
      out_st, Wb_pack, Wpc_pack, Whd_pack, b_pc, b_hd, out_hd, out_pc, out_bn);
}

// Round 8
// 512.308 us; speedup vs baseline: 2.2504x; 2.2504x over previous
//
#include <hip/hip_runtime.h>

#define TT 100
#define BB 2048
#define NI 3
#define NU 128
#define NB 256
#define NPC 256
#define NHD 12

typedef __attribute__((ext_vector_type(8))) short short8;
typedef __attribute__((ext_vector_type(4))) float f32x4;

__device__ __forceinline__ float fast_sigmoid(float x) {
  return 1.0f / (1.0f + __expf(-x));
}
__device__ __forceinline__ float fast_tanh(float x) {
  return 1.0f - 2.0f / (__expf(2.0f * x) + 1.0f);
}
__device__ __forceinline__ short f2bf(float f) {
  uint32_t u = __float_as_uint(f);
  u += 0x7FFF + ((u >> 16) & 1);  // RNE
  return (short)(u >> 16);
}
__device__ __forceinline__ float bf2f(short s) {
  return __uint_as_float(((uint32_t)(uint16_t)s) << 16);
}
// LDS-only barrier: leaves global (vmcnt) stores in flight across the barrier.
__device__ __forceinline__ void lds_barrier() {
  asm volatile("s_waitcnt lgkmcnt(0)" ::: "memory");
  __builtin_amdgcn_s_barrier();
}

// ---------------------------------------------------------------------------
// h0 = concat(init_pc, init_hd) @ W_embed + b_embed     [B, NU]
// ---------------------------------------------------------------------------
__global__ __launch_bounds__(256) void embed_kernel(
    const float* __restrict__ init_pc, const float* __restrict__ init_hd,
    const float* __restrict__ W_embed, const float* __restrict__ b_embed,
    float* __restrict__ h0) {
  __shared__ float pcs[2][NPC];
  __shared__ float hds[2][NHD];
  const int tid = threadIdx.x;
  const int b0 = blockIdx.x * 2;

  for (int idx = tid; idx < 2 * NPC; idx += 256)
    pcs[idx >> 8][idx & 255] =
        init_pc[(size_t)(b0 + (idx >> 8)) * NPC + (idx & 255)];
  if (tid < 2 * NHD) {
    int rr = tid / NHD, cc = tid - rr * NHD;
    hds[rr][cc] = init_hd[(size_t)(b0 + rr) * NHD + cc];
  }
  __syncthreads();

  const int half = tid >> 7;
  const int j = tid & 127;
  const float* Wp = W_embed + j;
  float a0 = 0.f, a1 = 0.f, a2 = 0.f, a3 = 0.f;
#pragma unroll 4
  for (int k = 0; k < NPC; k += 4) {
    a0 = fmaf(pcs[half][k + 0], Wp[(k + 0) * NU], a0);
    a1 = fmaf(pcs[half][k + 1], Wp[(k + 1) * NU], a1);
    a2 = fmaf(pcs[half][k + 2], Wp[(k + 2) * NU], a2);
    a3 = fmaf(pcs[half][k + 3], Wp[(k + 3) * NU], a3);
  }
#pragma unroll
  for (int k = 0; k < NHD; ++k)
    a0 = fmaf(hds[half][k], Wp[(NPC + k) * NU], a0);
  float acc = b_embed[j] + ((a0 + a1) + (a2 + a3));
  h0[(size_t)(b0 + half) * NU + j] = acc;
}

// ---------------------------------------------------------------------------
// Pre-pack GRU weights as bf16 MFMA B-fragments into workspace.
// frag f (1KB = 64 lanes x short8):
//   f in [0,96):    hi of U_g, g=f>>5 (0=Uz,1=Ur,2=Uh), nt=(f>>2)&7, kt=f&3
//   f in [96,128):  lo of Uh, nt=(f>>2)&7, kt=f&3
//   f in [128,152): augmented x-proj frag: w=f-128, g=w>>3, nt=w&7,
//                   B[k][col]: k<3 -> W_g[k][col], k==3 -> bias_g[col], else 0
// ---------------------------------------------------------------------------
__global__ __launch_bounds__(256) void prepack_gru_kernel(
    const float* __restrict__ Uz, const float* __restrict__ Ur,
    const float* __restrict__ Uh, const float* __restrict__ Wz,
    const float* __restrict__ Wr, const float* __restrict__ Wh,
    const float* __restrict__ bz, const float* __restrict__ br,
    const float* __restrict__ bh, short* __restrict__ gfrags) {
  int t = blockIdx.x * 256 + threadIdx.x;
  if (t >= 152 * 64) return;
  const int f = t >> 6, lane = t & 63;
  const int ln15 = lane & 15, g4 = lane >> 4;
  short8 p;
  if (f < 128) {
    const int g = f >> 5;  // 3 for the Uh-lo band
    const int nt = (f >> 2) & 7, kt = f & 3;
    const float* U = (g == 0) ? Uz : (g == 1) ? Ur : Uh;
#pragma unroll
    for (int e = 0; e < 8; ++e) {
      const float v = U[(kt * 32 + g4 * 8 + e) * NU + nt * 16 + ln15];
      const short hi = f2bf(v);
      p[e] = (f < 96) ? hi : f2bf(v - bf2f(hi));
    }
  } else {
    const int w = f - 128;
    const int g = w >> 3, nt = w & 7;
    const float* W = (g == 0) ? Wz : (g == 1) ? Wr : Wh;
    const float* bb = (g == 0) ? bz : (g == 1) ? br : bh;
    const int col = nt * 16 + ln15;
#pragma unroll
    for (int e = 0; e < 8; ++e) {
      const int k = g4 * 8 + e;
      float v = 0.0f;
      if (k < 3) v = W[k * NU + col];
      if (k == 3) v = bb[col];
      p[e] = f2bf(v);
    }
  }
  *((short8*)gfrags + (f * 64 + lane)) = p;
}

// ---------------------------------------------------------------------------
// GRU scan, decoupled-block TLP. 512 blocks x 4 batch rows (M padded to 16);
// 256 thr = 4 waves; wave w owns feature cols [32w,32w+32) (2 N-tiles).
// launch_bounds(256,2): VGPR<=256, 2 independent blocks/CU -> 2 waves/SIMD
// from DIFFERENT barrier groups (phase overlap hides latency).
// U hi (z,r,h) + Uh lo in VGPRs (128); augmented x-proj frags in LDS.
// 2-term gates, 3-term h-tilde (R7-proven numerics, absmax ~2.3e-2).
// ---------------------------------------------------------------------------
__global__ __launch_bounds__(256, 2) void gru_pipe_kernel(
    const float* __restrict__ x, const float* __restrict__ h0,
    const short* __restrict__ gfrags, float* __restrict__ states,
    float* __restrict__ final_state) {
  __shared__ short h_hi[16 * 128];
  __shared__ short h_lo[16 * 128];
  __shared__ short p_hi[16 * 128];
  __shared__ short p_lo[16 * 128];
  __shared__ short8 waug[24 * 64];  // 24 KB: x-proj frags for 3 gates x 8 nt
  __shared__ float xs[TT][4][4];    // 6.4 KB: x for all T, [r][3]=1.0

  const int tid = threadIdx.x;
  const int lane = tid & 63;
  const int w = tid >> 6;  // 0..3
  const int ln15 = lane & 15, g4 = lane >> 4;
  const int row0 = blockIdx.x * 4;

  // ---- stage Waug fragments ----
  for (int i = tid; i < 24 * 64; i += 256)
    waug[i] = *((const short8*)gfrags + (size_t)(128 + (i >> 6)) * 64 + (i & 63));

  // ---- preload x for all T (pad slot = 1.0 -> bias row of aug fragment) ----
  for (int i = tid; i < TT * 16; i += 256) {
    const int t = i >> 4, rem = i & 15, r = rem >> 2, c = rem & 3;
    ((float*)xs)[i] = (c < 3) ? x[(size_t)(t * BB + row0 + r) * NI + c] : 1.0f;
  }

  // ---- U fragments -> VGPRs (2 tiles each) ----
  short8 Uzh[2][4], Urh[2][4], Uhh[2][4], Uhl[2][4];
#pragma unroll
  for (int t2 = 0; t2 < 2; ++t2) {
    const int nt = w * 2 + t2;
#pragma unroll
    for (int kt = 0; kt < 4; ++kt) {
      Uzh[t2][kt] = *((const short8*)gfrags + (size_t)(nt * 4 + kt) * 64 + lane);
      Urh[t2][kt] =
          *((const short8*)gfrags + (size_t)(32 + nt * 4 + kt) * 64 + lane);
      Uhh[t2][kt] =
          *((const short8*)gfrags + (size_t)(64 + nt * 4 + kt) * 64 + lane);
      Uhl[t2][kt] =
          *((const short8*)gfrags + (size_t)(96 + nt * 4 + kt) * 64 + lane);
    }
  }

  // ---- fragment byte offsets (verified swizzle) ----
  int foff[4];
#pragma unroll
  for (int kt = 0; kt < 4; ++kt)
    foff[kt] = ln15 * 256 + ((kt * 64 + g4 * 16) ^ ((ln15 & 7) << 4));
  int woff[2][4];
#pragma unroll
  for (int t2 = 0; t2 < 2; ++t2)
#pragma unroll
    for (int q = 0; q < 4; ++q) {
      const int row = g4 * 4 + q;
      const int col = w * 32 + t2 * 16 + ln15;
      woff[t2][q] = row * 256 + ((col * 2) ^ ((row & 7) << 4));
    }

  // ---- init h regs + planes (rows 4-15 pad = 0); zero p planes ----
  float hreg[2][4];
#pragma unroll
  for (int t2 = 0; t2 < 2; ++t2)
#pragma unroll
    for (int q = 0; q < 4; ++q) {
      const int row = g4 * 4 + q;
      const int col = w * 32 + t2 * 16 + ln15;
      const float v = (row < 4) ? h0[(size_t)(row0 + row) * NU + col] : 0.0f;
      hreg[t2][q] = v;
      const short hi = f2bf(v);
      *(short*)((char*)h_hi + woff[t2][q]) = hi;
      *(short*)((char*)h_lo + woff[t2][q]) = f2bf(v - bf2f(hi));
      *(short*)((char*)p_hi + woff[t2][q]) = 0;
      *(short*)((char*)p_lo + woff[t2][q]) = 0;
    }
  __syncthreads();

  const f32x4 zero = {0.f, 0.f, 0.f, 0.f};

  for (int t = 0; t < TT; ++t) {
    // ---- A-fragments of h + augmented x fragment ----
    short8 ahi[4], alo[4];
#pragma unroll
    for (int kt = 0; kt < 4; ++kt) {
      ahi[kt] = *(const short8*)((const char*)h_hi + foff[kt]);
      alo[kt] = *(const short8*)((const char*)h_lo + foff[kt]);
    }
    short8 ax = {0, 0, 0, 0, 0, 0, 0, 0};
    {
      const float4 xv = *(const float4*)&xs[t][ln15 & 3][0];
      if (g4 == 0) {
        ax[0] = f2bf(xv.x);
        ax[1] = f2bf(xv.y);
        ax[2] = f2bf(xv.z);
        ax[3] = f2bf(xv.w);  // 1.0 -> bias row
      }
    }

    // ================= phase A: z and r (2-term, 8 chains) =================
    f32x4 zA[2], zB[2], rA[2], rB[2];
#pragma unroll
    for (int t2 = 0; t2 < 2; ++t2) {
      const int nt = w * 2 + t2;
      zA[t2] = __builtin_amdgcn_mfma_f32_16x16x32_bf16(
          ax, waug[(0 + nt) * 64 + lane], zero, 0, 0, 0);
      rA[t2] = __builtin_amdgcn_mfma_f32_16x16x32_bf16(
          ax, waug[(8 + nt) * 64 + lane], zero, 0, 0, 0);
      zB[t2] = zero;
      rB[t2] = zero;
    }
#pragma unroll
    for (int kt = 0; kt < 4; ++kt)
#pragma unroll
      for (int t2 = 0; t2 < 2; ++t2) {
        zA[t2] = __builtin_amdgcn_mfma_f32_16x16x32_bf16(ahi[kt], Uzh[t2][kt],
                                                         zA[t2], 0, 0, 0);
        rA[t2] = __builtin_amdgcn_mfma_f32_16x16x32_bf16(ahi[kt], Urh[t2][kt],
                                                         rA[t2], 0, 0, 0);
        zB[t2] = __builtin_amdgcn_mfma_f32_16x16x32_bf16(alo[kt], Uzh[t2][kt],
                                                         zB[t2], 0, 0, 0);
        rB[t2] = __builtin_amdgcn_mfma_f32_16x16x32_bf16(alo[kt], Urh[t2][kt],
                                                         rB[t2], 0, 0, 0);
      }

    float zg[2][4];
#pragma unroll
    for (int t2 = 0; t2 < 2; ++t2)
#pragma unroll
      for (int q = 0; q < 4; ++q)
        zg[t2][q] = fast_sigmoid(zA[t2][q] + zB[t2][q]);
    if (g4 == 0) {
#pragma unroll
      for (int t2 = 0; t2 < 2; ++t2)
#pragma unroll
        for (int q = 0; q < 4; ++q) {
          const float rh =
              fast_sigmoid(rA[t2][q] + rB[t2][q]) * hreg[t2][q];
          const short hi = f2bf(rh);
          *(short*)((char*)p_hi + woff[t2][q]) = hi;
          *(short*)((char*)p_lo + woff[t2][q]) = f2bf(rh - bf2f(hi));
        }
    }
    lds_barrier();  // rh planes visible

    // ============== phase B: h-tilde (3-term, 6 chains) + update ===========
    short8 phi[4], plo[4];
#pragma unroll
    for (int kt = 0; kt < 4; ++kt) {
      phi[kt] = *(const short8*)((const char*)p_hi + foff[kt]);
      plo[kt] = *(const short8*)((const char*)p_lo + foff[kt]);
    }
    f32x4 hA[2], hB[2], hC[2];
#pragma unroll
    for (int t2 = 0; t2 < 2; ++t2) {
      const int nt = w * 2 + t2;
      hA[t2] = __builtin_amdgcn_mfma_f32_16x16x32_bf16(
          ax, waug[(16 + nt) * 64 + lane], zero, 0, 0, 0);
      hB[t2] = zero;
      hC[t2] = zero;
    }
#pragma unroll
    for (int kt = 0; kt < 4; ++kt)
#pragma unroll
      for (int t2 = 0; t2 < 2; ++t2) {
        hA[t2] = __builtin_amdgcn_mfma_f32_16x16x32_bf16(phi[kt], Uhh[t2][kt],
                                                         hA[t2], 0, 0, 0);
        hB[t2] = __builtin_amdgcn_mfma_f32_16x16x32_bf16(plo[kt], Uhh[t2][kt],
                                                         hB[t2], 0, 0, 0);
        hC[t2] = __builtin_amdgcn_mfma_f32_16x16x32_bf16(phi[kt], Uhl[t2][kt],
                                                         hC[t2], 0, 0, 0);
      }
#pragma unroll
    for (int t2 = 0; t2 < 2; ++t2)
#pragma unroll
      for (int q = 0; q < 4; ++q) {
        const float htw = fast_tanh(hA[t2][q] + hB[t2][q] + hC[t2][q]);
        hreg[t2][q] = fmaf(zg[t2][q], htw - hreg[t2][q], hreg[t2][q]);
      }
    if (g4 == 0) {
#pragma unroll
      for (int t2 = 0; t2 < 2; ++t2)
#pragma unroll
        for (int q = 0; q < 4; ++q) {
          const short hi = f2bf(hreg[t2][q]);
          *(short*)((char*)h_hi + woff[t2][q]) = hi;
          *(short*)((char*)h_lo + woff[t2][q]) = f2bf(hreg[t2][q] - bf2f(hi));
          // fire-and-forget HBM store (no vmcnt wait in loop)
          states[((size_t)t * BB + row0 + g4 * 4 + q) * NU + w * 32 +
                 t2 * 16 + ln15] = hreg[t2][q];
        }
    }
    lds_barrier();  // h planes visible
  }

  if (g4 == 0) {
#pragma unroll
    for (int t2 = 0; t2 < 2; ++t2)
#pragma unroll
      for (int q = 0; q < 4; ++q)
        final_state[(size_t)(row0 + g4 * 4 + q) * NU + w * 32 + t2 * 16 +
                    ln15] = hreg[t2][q];
  }
}

// ---------------------------------------------------------------------------
// Pre-pack heads weights into bf16 MFMA B-fragment order (unchanged).
// ---------------------------------------------------------------------------
__global__ __launch_bounds__(256) void prepack_kernel(
    const float* __restrict__ Wb, const float* __restrict__ Wpc,
    const float* __restrict__ Whd, short* __restrict__ Wb_pack,
    short* __restrict__ Wpc_pack, short* __restrict__ Whd_pack) {
  int t = blockIdx.x * 256 + threadIdx.x;
  if (t >= 200 * 64) return;
  int fb = t >> 6, lane = t & 63;
  const float* W;
  short* out;
  int n_tile, k_tile, N, local;
  if (fb < 64) {
    W = Wb; out = Wb_pack; local = fb; n_tile = fb >> 2; k_tile = fb & 3; N = 256;
  } else if (fb < 192) {
    int f = fb - 64;
    W = Wpc; out = Wpc_pack; local = f; n_tile = f >> 3; k_tile = f & 7; N = 256;
  } else {
    int f = fb - 192;
    W = Whd; out = Whd_pack; local = f; n_tile = 0; k_tile = f; N = 12;
  }
  short8 p;
#pragma unroll
  for (int e = 0; e < 8; ++e) {
    int k = k_tile * 32 + (lane >> 4) * 8 + e;
    int colc = n_tile * 16 + (lane & 15);
    float v = (colc < N) ? W[k * N + colc] : 0.0f;
    p[e] = f2bf(v);
  }
  *((short8*)out + (local * 64 + lane)) = p;
}

// ---------------------------------------------------------------------------
// MFMA heads: 64 rows/block, 256 threads (4 waves, 16-row stripe each).
// ---------------------------------------------------------------------------
__global__ __launch_bounds__(256, 3) void heads_mfma_kernel(
    const float* __restrict__ states, const short* __restrict__ Wb_pack,
    const short* __restrict__ Wpc_pack, const short* __restrict__ Whd_pack,
    const float* __restrict__ b_pc, const float* __restrict__ b_hd,
    float* __restrict__ out_hd, float* __restrict__ out_pc,
    float* __restrict__ out_bn) {
  __shared__ short s_lds[64 * 128];   // 16 KB
  __shared__ short bn_lds[64 * 256];  // 32 KB
  const int tid = threadIdx.x;
  const size_t R0 = (size_t)blockIdx.x * 64;

  for (int c = tid; c < 1024; c += 256) {
    int row = c >> 4, s16 = c & 15;
    const float* src = states + (R0 + row) * 128 + s16 * 8;
    float4 v0 = *(const float4*)src;
    float4 v1 = *(const float4*)(src + 4);
    short8 p;
    p[0] = f2bf(v0.x); p[1] = f2bf(v0.y); p[2] = f2bf(v0.z); p[3] = f2bf(v0.w);
    p[4] = f2bf(v1.x); p[5] = f2bf(v1.y); p[6] = f2bf(v1.z); p[7] = f2bf(v1.w);
    int byte = row * 256 + ((s16 * 16) ^ ((row & 7) << 4));
    *(short8*)((char*)s_lds + byte) = p;
  }
  __syncthreads();

  const int lane = tid & 63;
  const int wave = tid >> 6;
  const int ln15 = lane & 15;
  const int ln4 = lane >> 4;
  const int r0 = wave * 16;

  {
    short8 a[4];
#pragma unroll
    for (int kt = 0; kt < 4; ++kt) {
      int byte =
          (r0 + ln15) * 256 + ((kt * 64 + ln4 * 16) ^ ((ln15 & 7) << 4));
      a[kt] = *(const short8*)((const char*)s_lds + byte);
    }
#pragma unroll
    for (int nt = 0; nt < 16; ++nt) {
      f32x4 acc = {0.f, 0.f, 0.f, 0.f};
      const short8* bp = (const short8*)Wb_pack + (nt * 4) * 64 + lane;
#pragma unroll
      for (int kt = 0; kt < 4; ++kt)
        acc = __builtin_amdgcn_mfma_f32_16x16x32_bf16(a[kt], bp[kt * 64], acc,
                                                      0, 0, 0);
      int colc = nt * 16 + ln15;
#pragma unroll
      for (int q = 0; q < 4; ++q) {
        int row = r0 + ln4 * 4 + q;
        out_bn[(R0 + row) * NB + colc] = acc[q];
        int byte = row * 512 + ((colc * 2) ^ ((row & 7) << 4));
        *(short*)((char*)bn_lds + byte) = f2bf(acc[q]);
      }
    }
  }
  __syncthreads();

  {
    short8 ab[8];
#pragma unroll
    for (int kt = 0; kt < 8; ++kt) {
      int byte =
          (r0 + ln15) * 512 + ((kt * 64 + ln4 * 16) ^ ((ln15 & 7) << 4));
      ab[kt] = *(const short8*)((const char*)bn_lds + byte);
    }
#pragma unroll
    for (int nt = 0; nt < 16; ++nt) {
      int colc = nt * 16 + ln15;
      float bias = b_pc[colc];
      f32x4 acc = {bias, bias, bias, bias};
      const short8* bp = (const short8*)Wpc_pack + (nt * 8) * 64 + lane;
#pragma unroll
      for (int kt = 0; kt < 8; ++kt)
        acc = __builtin_amdgcn_mfma_f32_16x16x32_bf16(ab[kt], bp[kt * 64], acc,
                                                      0, 0, 0);
#pragma unroll
      for (int q = 0; q < 4; ++q)
        out_pc[(R0 + r0 + ln4 * 4 + q) * NPC + colc] = acc[q];
    }
    {
      int colc = ln15;
      float bias = (colc < NHD) ? b_hd[colc] : 0.0f;
      f32x4 acc = {bias, bias, bias, bias};
      const short8* bp = (const short8*)Whd_pack + lane;
#pragma unroll
      for (int kt = 0; kt < 8; ++kt)
        acc = __builtin_amdgcn_mfma_f32_16x16x32_bf16(ab[kt], bp[kt * 64], acc,
                                                      0, 0, 0);
      if (colc < NHD) {
#pragma unroll
        for (int q = 0; q < 4; ++q)
          out_hd[(R0 + r0 + ln4 * 4 + q) * NHD + colc] = acc[q];
      }
    }
  }
}

// ---------------------------------------------------------------------------
extern "C" void kernel_launch(void* const* d_in, const int* in_sizes, int n_in,
                              void* d_out, int out_size, void* d_ws,
                              size_t ws_size, hipStream_t stream) {
  (void)in_sizes;
  (void)n_in;
  (void)out_size;
  (void)ws_size;
  const float* x = (const float*)d_in[0];
  const float* init_pc = (const float*)d_in[1];
  const float* init_hd = (const float*)d_in[2];
  const float* Wz = (const float*)d_in[3];
  const float* Wr = (const float*)d_in[4];
  const float* Wh = (const float*)d_in[5];
  const float* Uz = (const float*)d_in[6];
  const float* Ur = (const float*)d_in[7];
  const float* Uh = (const float*)d_in[8];
  const float* bz = (const float*)d_in[9];
  const float* br = (const float*)d_in[10];
  const float* bh = (const float*)d_in[11];
  const float* W_embed = (const float*)d_in[12];
  const float* b_embed = (const float*)d_in[13];
  const float* W_bneck = (const float*)d_in[14];
  const float* W_pc = (const float*)d_in[15];
  const float* b_pc = (const float*)d_in[16];
  const float* W_hd = (const float*)d_in[17];
  const float* b_hd = (const float*)d_in[18];

  float* out = (float*)d_out;
  float* out_hd = out;
  float* out_pc = out_hd + (size_t)TT * BB * NHD;
  float* out_bn = out_pc + (size_t)TT * BB * NPC;
  float* out_st = out_bn + (size_t)TT * BB * NB;
  float* out_fs = out_st + (size_t)TT * BB * NU;

  float* h0 = (float*)d_ws;                            // 1 MB
  short* Wb_pack = (short*)((char*)d_ws + (1 << 20));  // 64 KB
  short* Wpc_pack = Wb_pack + 64 * 64 * 8;             // 128 KB
  short* Whd_pack = Wpc_pack + 128 * 64 * 8;           // 8 KB
  short* gru_frags = (short*)((char*)d_ws + (1 << 20) + 200 * 1024);  // 152 KB

  prepack_kernel<<<50, 256, 0, stream>>>(W_bneck, W_pc, W_hd, Wb_pack,
                                         Wpc_pack, Whd_pack);
  prepack_gru_kernel<<<38, 256, 0, stream>>>(Uz, Ur, Uh, Wz, Wr, Wh, bz, br,
                                             bh, gru_frags);
  embed_kernel<<<BB / 2, 256, 0, stream>>>(init_pc, init_hd, W_embed, b_embed,
                                           h0);
  gru_pipe_kernel<<<BB / 4, 256, 0, stream>>>(x, h0, gru_frags, out_st,
                                              out_fs);
  heads_mfma_kernel<<<(TT * BB) / 64, 256, 0, stream>>>(
      out_st, Wb_pack, Wpc_pack, Whd_pack, b_pc, b_hd, out_hd, out_pc, out_bn);
}

// Round 9
// 510.357 us; speedup vs baseline: 2.2590x; 1.0038x over previous
//
#include <hip/hip_runtime.h>

#define TT 100
#define BB 2048
#define NI 3
#define NU 128
#define NB 256
#define NPC 256
#define NHD 12

typedef __attribute__((ext_vector_type(8))) short short8;
typedef __attribute__((ext_vector_type(4))) float f32x4;

__device__ __forceinline__ float fast_sigmoid(float x) {
  return 1.0f / (1.0f + __expf(-x));
}
__device__ __forceinline__ float fast_tanh(float x) {
  return 1.0f - 2.0f / (__expf(2.0f * x) + 1.0f);
}
__device__ __forceinline__ short f2bf(float f) {
  uint32_t u = __float_as_uint(f);
  u += 0x7FFF + ((u >> 16) & 1);  // RNE
  return (short)(u >> 16);
}
__device__ __forceinline__ float bf2f(short s) {
  return __uint_as_float(((uint32_t)(uint16_t)s) << 16);
}
// LDS-only barrier: leaves global (vmcnt) stores in flight across the barrier.
__device__ __forceinline__ void lds_barrier() {
  asm volatile("s_waitcnt lgkmcnt(0)" ::: "memory");
  __builtin_amdgcn_s_barrier();
}

// ---------------------------------------------------------------------------
// h0 = concat(init_pc, init_hd) @ W_embed + b_embed     [B, NU]
// ---------------------------------------------------------------------------
__global__ __launch_bounds__(256) void embed_kernel(
    const float* __restrict__ init_pc, const float* __restrict__ init_hd,
    const float* __restrict__ W_embed, const float* __restrict__ b_embed,
    float* __restrict__ h0) {
  __shared__ float pcs[2][NPC];
  __shared__ float hds[2][NHD];
  const int tid = threadIdx.x;
  const int b0 = blockIdx.x * 2;

  for (int idx = tid; idx < 2 * NPC; idx += 256)
    pcs[idx >> 8][idx & 255] =
        init_pc[(size_t)(b0 + (idx >> 8)) * NPC + (idx & 255)];
  if (tid < 2 * NHD) {
    int rr = tid / NHD, cc = tid - rr * NHD;
    hds[rr][cc] = init_hd[(size_t)(b0 + rr) * NHD + cc];
  }
  __syncthreads();

  const int half = tid >> 7;
  const int j = tid & 127;
  const float* Wp = W_embed + j;
  float a0 = 0.f, a1 = 0.f, a2 = 0.f, a3 = 0.f;
#pragma unroll 4
  for (int k = 0; k < NPC; k += 4) {
    a0 = fmaf(pcs[half][k + 0], Wp[(k + 0) * NU], a0);
    a1 = fmaf(pcs[half][k + 1], Wp[(k + 1) * NU], a1);
    a2 = fmaf(pcs[half][k + 2], Wp[(k + 2) * NU], a2);
    a3 = fmaf(pcs[half][k + 3], Wp[(k + 3) * NU], a3);
  }
#pragma unroll
  for (int k = 0; k < NHD; ++k)
    a0 = fmaf(hds[half][k], Wp[(NPC + k) * NU], a0);
  float acc = b_embed[j] + ((a0 + a1) + (a2 + a3));
  h0[(size_t)(b0 + half) * NU + j] = acc;
}

// ---------------------------------------------------------------------------
// Pre-pack GRU weights as bf16 MFMA B-fragments into workspace.
// frag f (1KB = 64 lanes x short8):
//   f in [0,96):    hi of U_g, g=f>>5 (0=Uz,1=Ur,2=Uh), nt=(f>>2)&7, kt=f&3
//   f in [96,128):  lo of Uh, nt=(f>>2)&7, kt=f&3
//   f in [128,152): augmented x-proj frag: w=f-128, g=w>>3, nt=w&7,
//                   B[k][col]: k<3 -> W_g[k][col], k==3 -> bias_g[col], else 0
// ---------------------------------------------------------------------------
__global__ __launch_bounds__(256) void prepack_gru_kernel(
    const float* __restrict__ Uz, const float* __restrict__ Ur,
    const float* __restrict__ Uh, const float* __restrict__ Wz,
    const float* __restrict__ Wr, const float* __restrict__ Wh,
    const float* __restrict__ bz, const float* __restrict__ br,
    const float* __restrict__ bh, short* __restrict__ gfrags) {
  int t = blockIdx.x * 256 + threadIdx.x;
  if (t >= 152 * 64) return;
  const int f = t >> 6, lane = t & 63;
  const int ln15 = lane & 15, g4 = lane >> 4;
  short8 p;
  if (f < 128) {
    const int g = f >> 5;  // 3 for the Uh-lo band
    const int nt = (f >> 2) & 7, kt = f & 3;
    const float* U = (g == 0) ? Uz : (g == 1) ? Ur : Uh;
#pragma unroll
    for (int e = 0; e < 8; ++e) {
      const float v = U[(kt * 32 + g4 * 8 + e) * NU + nt * 16 + ln15];
      const short hi = f2bf(v);
      p[e] = (f < 96) ? hi : f2bf(v - bf2f(hi));
    }
  } else {
    const int w = f - 128;
    const int g = w >> 3, nt = w & 7;
    const float* W = (g == 0) ? Wz : (g == 1) ? Wr : Wh;
    const float* bb = (g == 0) ? bz : (g == 1) ? br : bh;
    const int col = nt * 16 + ln15;
#pragma unroll
    for (int e = 0; e < 8; ++e) {
      const int k = g4 * 8 + e;
      float v = 0.0f;
      if (k < 3) v = W[k * NU + col];
      if (k == 3) v = bb[col];
      p[e] = f2bf(v);
    }
  }
  *((short8*)gfrags + (f * 64 + lane)) = p;
}

// ---------------------------------------------------------------------------
// GRU scan, decoupled-block TLP + FORCED-RESIDENT U fragments.
// 512 blocks x 4 batch rows (M padded to 16); 256 thr = 4 waves; wave w owns
// feature cols [32w,32w+32). launch_bounds(256,2): 2 independent blocks/CU.
// U frags pass through an opaque asm fence after load -> compiler cannot
// rematerialize the global loads inside the loop (R8: VGPR=108 proved it did;
// cost = 32 L2 round-trips/wave/step). Budget ~230 VGPR < 256 cap.
// 2-term gates, 3-term h-tilde (proven numerics, absmax ~2.3e-2).
// ---------------------------------------------------------------------------
__global__ __launch_bounds__(256, 2) void gru_pipe_kernel(
    const float* __restrict__ x, const float* __restrict__ h0,
    const short* __restrict__ gfrags, float* __restrict__ states,
    float* __restrict__ final_state) {
  __shared__ short h_hi[16 * 128];
  __shared__ short h_lo[16 * 128];
  __shared__ short p_hi[16 * 128];
  __shared__ short p_lo[16 * 128];
  __shared__ short8 waug[24 * 64];  // 24 KB: x-proj frags for 3 gates x 8 nt
  __shared__ float xs[TT][4][4];    // 6.4 KB: x for all T, [r][3]=1.0

  const int tid = threadIdx.x;
  const int lane = tid & 63;
  const int w = tid >> 6;  // 0..3
  const int ln15 = lane & 15, g4 = lane >> 4;
  const int row0 = blockIdx.x * 4;

  // ---- stage Waug fragments ----
  for (int i = tid; i < 24 * 64; i += 256)
    waug[i] = *((const short8*)gfrags + (size_t)(128 + (i >> 6)) * 64 + (i & 63));

  // ---- preload x for all T (pad slot = 1.0 -> bias row of aug fragment) ----
  for (int i = tid; i < TT * 16; i += 256) {
    const int t = i >> 4, rem = i & 15, r = rem >> 2, c = rem & 3;
    ((float*)xs)[i] = (c < 3) ? x[(size_t)(t * BB + row0 + r) * NI + c] : 1.0f;
  }

  // ---- U fragments -> VGPRs (2 tiles each) ----
  short8 Uzh[2][4], Urh[2][4], Uhh[2][4], Uhl[2][4];
#pragma unroll
  for (int t2 = 0; t2 < 2; ++t2) {
    const int nt = w * 2 + t2;
#pragma unroll
    for (int kt = 0; kt < 4; ++kt) {
      Uzh[t2][kt] = *((const short8*)gfrags + (size_t)(nt * 4 + kt) * 64 + lane);
      Urh[t2][kt] =
          *((const short8*)gfrags + (size_t)(32 + nt * 4 + kt) * 64 + lane);
      Uhh[t2][kt] =
          *((const short8*)gfrags + (size_t)(64 + nt * 4 + kt) * 64 + lane);
      Uhl[t2][kt] =
          *((const short8*)gfrags + (size_t)(96 + nt * 4 + kt) * 64 + lane);
    }
  }
  // ---- residency fence: opaque producer -> no rematerialization in-loop ----
#pragma unroll
  for (int t2 = 0; t2 < 2; ++t2)
#pragma unroll
    for (int kt = 0; kt < 4; ++kt) {
      asm volatile("" : "+v"(Uzh[t2][kt]));
      asm volatile("" : "+v"(Urh[t2][kt]));
      asm volatile("" : "+v"(Uhh[t2][kt]));
      asm volatile("" : "+v"(Uhl[t2][kt]));
    }

  // ---- fragment byte offsets (verified swizzle) ----
  int foff[4];
#pragma unroll
  for (int kt = 0; kt < 4; ++kt)
    foff[kt] = ln15 * 256 + ((kt * 64 + g4 * 16) ^ ((ln15 & 7) << 4));
  int woff[2][4];
#pragma unroll
  for (int t2 = 0; t2 < 2; ++t2)
#pragma unroll
    for (int q = 0; q < 4; ++q) {
      const int row = g4 * 4 + q;
      const int col = w * 32 + t2 * 16 + ln15;
      woff[t2][q] = row * 256 + ((col * 2) ^ ((row & 7) << 4));
    }

  // ---- init h regs + planes (rows 4-15 pad = 0); zero p planes ----
  float hreg[2][4];
#pragma unroll
  for (int t2 = 0; t2 < 2; ++t2)
#pragma unroll
    for (int q = 0; q < 4; ++q) {
      const int row = g4 * 4 + q;
      const int col = w * 32 + t2 * 16 + ln15;
      const float v = (row < 4) ? h0[(size_t)(row0 + row) * NU + col] : 0.0f;
      hreg[t2][q] = v;
      const short hi = f2bf(v);
      *(short*)((char*)h_hi + woff[t2][q]) = hi;
      *(short*)((char*)h_lo + woff[t2][q]) = f2bf(v - bf2f(hi));
      *(short*)((char*)p_hi + woff[t2][q]) = 0;
      *(short*)((char*)p_lo + woff[t2][q]) = 0;
    }
  __syncthreads();

  const f32x4 zero = {0.f, 0.f, 0.f, 0.f};

  for (int t = 0; t < TT; ++t) {
    // ---- A-fragments of h + augmented x fragment ----
    short8 ahi[4], alo[4];
#pragma unroll
    for (int kt = 0; kt < 4; ++kt) {
      ahi[kt] = *(const short8*)((const char*)h_hi + foff[kt]);
      alo[kt] = *(const short8*)((const char*)h_lo + foff[kt]);
    }
    short8 ax = {0, 0, 0, 0, 0, 0, 0, 0};
    {
      const float4 xv = *(const float4*)&xs[t][ln15 & 3][0];
      if (g4 == 0) {
        ax[0] = f2bf(xv.x);
        ax[1] = f2bf(xv.y);
        ax[2] = f2bf(xv.z);
        ax[3] = f2bf(xv.w);  // 1.0 -> bias row
      }
    }

    // ================= phase A: z and r (2-term, 8 chains) =================
    f32x4 zA[2], zB[2], rA[2], rB[2];
#pragma unroll
    for (int t2 = 0; t2 < 2; ++t2) {
      const int nt = w * 2 + t2;
      zA[t2] = __builtin_amdgcn_mfma_f32_16x16x32_bf16(
          ax, waug[(0 + nt) * 64 + lane], zero, 0, 0, 0);
      rA[t2] = __builtin_amdgcn_mfma_f32_16x16x32_bf16(
          ax, waug[(8 + nt) * 64 + lane], zero, 0, 0, 0);
      zB[t2] = zero;
      rB[t2] = zero;
    }
#pragma unroll
    for (int kt = 0; kt < 4; ++kt)
#pragma unroll
      for (int t2 = 0; t2 < 2; ++t2) {
        zA[t2] = __builtin_amdgcn_mfma_f32_16x16x32_bf16(ahi[kt], Uzh[t2][kt],
                                                         zA[t2], 0, 0, 0);
        rA[t2] = __builtin_amdgcn_mfma_f32_16x16x32_bf16(ahi[kt], Urh[t2][kt],
                                                         rA[t2], 0, 0, 0);
        zB[t2] = __builtin_amdgcn_mfma_f32_16x16x32_bf16(alo[kt], Uzh[t2][kt],
                                                         zB[t2], 0, 0, 0);
        rB[t2] = __builtin_amdgcn_mfma_f32_16x16x32_bf16(alo[kt], Urh[t2][kt],
                                                         rB[t2], 0, 0, 0);
      }

    float zg[2][4];
#pragma unroll
    for (int t2 = 0; t2 < 2; ++t2)
#pragma unroll
      for (int q = 0; q < 4; ++q)
        zg[t2][q] = fast_sigmoid(zA[t2][q] + zB[t2][q]);
    if (g4 == 0) {
#pragma unroll
      for (int t2 = 0; t2 < 2; ++t2)
#pragma unroll
        for (int q = 0; q < 4; ++q) {
          const float rh =
              fast_sigmoid(rA[t2][q] + rB[t2][q]) * hreg[t2][q];
          const short hi = f2bf(rh);
          *(short*)((char*)p_hi + woff[t2][q]) = hi;
          *(short*)((char*)p_lo + woff[t2][q]) = f2bf(rh - bf2f(hi));
        }
    }
    lds_barrier();  // rh planes visible

    // ============== phase B: h-tilde (3-term, 6 chains) + update ===========
    short8 phi[4], plo[4];
#pragma unroll
    for (int kt = 0; kt < 4; ++kt) {
      phi[kt] = *(const short8*)((const char*)p_hi + foff[kt]);
      plo[kt] = *(const short8*)((const char*)p_lo + foff[kt]);
    }
    f32x4 hA[2], hB[2], hC[2];
#pragma unroll
    for (int t2 = 0; t2 < 2; ++t2) {
      const int nt = w * 2 + t2;
      hA[t2] = __builtin_amdgcn_mfma_f32_16x16x32_bf16(
          ax, waug[(16 + nt) * 64 + lane], zero, 0, 0, 0);
      hB[t2] = zero;
      hC[t2] = zero;
    }
#pragma unroll
    for (int kt = 0; kt < 4; ++kt)
#pragma unroll
      for (int t2 = 0; t2 < 2; ++t2) {
        hA[t2] = __builtin_amdgcn_mfma_f32_16x16x32_bf16(phi[kt], Uhh[t2][kt],
                                                         hA[t2], 0, 0, 0);
        hB[t2] = __builtin_amdgcn_mfma_f32_16x16x32_bf16(plo[kt], Uhh[t2][kt],
                                                         hB[t2], 0, 0, 0);
        hC[t2] = __builtin_amdgcn_mfma_f32_16x16x32_bf16(phi[kt], Uhl[t2][kt],
                                                         hC[t2], 0, 0, 0);
      }
#pragma unroll
    for (int t2 = 0; t2 < 2; ++t2)
#pragma unroll
      for (int q = 0; q < 4; ++q) {
        const float htw = fast_tanh(hA[t2][q] + hB[t2][q] + hC[t2][q]);
        hreg[t2][q] = fmaf(zg[t2][q], htw - hreg[t2][q], hreg[t2][q]);
      }
    if (g4 == 0) {
#pragma unroll
      for (int t2 = 0; t2 < 2; ++t2)
#pragma unroll
        for (int q = 0; q < 4; ++q) {
          const short hi = f2bf(hreg[t2][q]);
          *(short*)((char*)h_hi + woff[t2][q]) = hi;
          *(short*)((char*)h_lo + woff[t2][q]) = f2bf(hreg[t2][q] - bf2f(hi));
          // fire-and-forget HBM store (no vmcnt wait in loop)
          states[((size_t)t * BB + row0 + g4 * 4 + q) * NU + w * 32 +
                 t2 * 16 + ln15] = hreg[t2][q];
        }
    }
    lds_barrier();  // h planes visible
  }

  if (g4 == 0) {
#pragma unroll
    for (int t2 = 0; t2 < 2; ++t2)
#pragma unroll
      for (int q = 0; q < 4; ++q)
        final_state[(size_t)(row0 + g4 * 4 + q) * NU + w * 32 + t2 * 16 +
                    ln15] = hreg[t2][q];
  }
}

// ---------------------------------------------------------------------------
// Pre-pack heads weights into bf16 MFMA B-fragment order (unchanged).
// ---------------------------------------------------------------------------
__global__ __launch_bounds__(256) void prepack_kernel(
    const float* __restrict__ Wb, const float* __restrict__ Wpc,
    const float* __restrict__ Whd, short* __restrict__ Wb_pack,
    short* __restrict__ Wpc_pack, short* __restrict__ Whd_pack) {
  int t = blockIdx.x * 256 + threadIdx.x;
  if (t >= 200 * 64) return;
  int fb = t >> 6, lane = t & 63;
  const float* W;
  short* out;
  int n_tile, k_tile, N, local;
  if (fb < 64) {
    W = Wb; out = Wb_pack; local = fb; n_tile = fb >> 2; k_tile = fb & 3; N = 256;
  } else if (fb < 192) {
    int f = fb - 64;
    W = Wpc; out = Wpc_pack; local = f; n_tile = f >> 3; k_tile = f & 7; N = 256;
  } else {
    int f = fb - 192;
    W = Whd; out = Whd_pack; local = f; n_tile = 0; k_tile = f; N = 12;
  }
  short8 p;
#pragma unroll
  for (int e = 0; e < 8; ++e) {
    int k = k_tile * 32 + (lane >> 4) * 8 + e;
    int colc = n_tile * 16 + (lane & 15);
    float v = (colc < N) ? W[k * N + colc] : 0.0f;
    p[e] = f2bf(v);
  }
  *((short8*)out + (local * 64 + lane)) = p;
}

// ---------------------------------------------------------------------------
// MFMA heads: 64 rows/block, 256 threads (4 waves, 16-row stripe each).
// ---------------------------------------------------------------------------
__global__ __launch_bounds__(256, 3) void heads_mfma_kernel(
    const float* __restrict__ states, const short* __restrict__ Wb_pack,
    const short* __restrict__ Wpc_pack, const short* __restrict__ Whd_pack,
    const float* __restrict__ b_pc, const float* __restrict__ b_hd,
    float* __restrict__ out_hd, float* __restrict__ out_pc,
    float* __restrict__ out_bn) {
  __shared__ short s_lds[64 * 128];   // 16 KB
  __shared__ short bn_lds[64 * 256];  // 32 KB
  const int tid = threadIdx.x;
  const size_t R0 = (size_t)blockIdx.x * 64;

  for (int c = tid; c < 1024; c += 256) {
    int row = c >> 4, s16 = c & 15;
    const float* src = states + (R0 + row) * 128 + s16 * 8;
    float4 v0 = *(const float4*)src;
    float4 v1 = *(const float4*)(src + 4);
    short8 p;
    p[0] = f2bf(v0.x); p[1] = f2bf(v0.y); p[2] = f2bf(v0.z); p[3] = f2bf(v0.w);
    p[4] = f2bf(v1.x); p[5] = f2bf(v1.y); p[6] = f2bf(v1.z); p[7] = f2bf(v1.w);
    int byte = row * 256 + ((s16 * 16) ^ ((row & 7) << 4));
    *(short8*)((char*)s_lds + byte) = p;
  }
  __syncthreads();

  const int lane = tid & 63;
  const int wave = tid >> 6;
  const int ln15 = lane & 15;
  const int ln4 = lane >> 4;
  const int r0 = wave * 16;

  {
    short8 a[4];
#pragma unroll
    for (int kt = 0; kt < 4; ++kt) {
      int byte =
          (r0 + ln15) * 256 + ((kt * 64 + ln4 * 16) ^ ((ln15 & 7) << 4));
      a[kt] = *(const short8*)((const char*)s_lds + byte);
    }
#pragma unroll
    for (int nt = 0; nt < 16; ++nt) {
      f32x4 acc = {0.f, 0.f, 0.f, 0.f};
      const short8* bp = (const short8*)Wb_pack + (nt * 4) * 64 + lane;
#pragma unroll
      for (int kt = 0; kt < 4; ++kt)
        acc = __builtin_amdgcn_mfma_f32_16x16x32_bf16(a[kt], bp[kt * 64], acc,
                                                      0, 0, 0);
      int colc = nt * 16 + ln15;
#pragma unroll
      for (int q = 0; q < 4; ++q) {
        int row = r0 + ln4 * 4 + q;
        out_bn[(R0 + row) * NB + colc] = acc[q];
        int byte = row * 512 + ((colc * 2) ^ ((row & 7) << 4));
        *(short*)((char*)bn_lds + byte) = f2bf(acc[q]);
      }
    }
  }
  __syncthreads();

  {
    short8 ab[8];
#pragma unroll
    for (int kt = 0; kt < 8; ++kt) {
      int byte =
          (r0 + ln15) * 512 + ((kt * 64 + ln4 * 16) ^ ((ln15 & 7) << 4));
      ab[kt] = *(const short8*)((const char*)bn_lds + byte);
    }
#pragma unroll
    for (int nt = 0; nt < 16; ++nt) {
      int colc = nt * 16 + ln15;
      float bias = b_pc[colc];
      f32x4 acc = {bias, bias, bias, bias};
      const short8* bp = (const short8*)Wpc_pack + (nt * 8) * 64 + lane;
#pragma unroll
      for (int kt = 0; kt < 8; ++kt)
        acc = __builtin_amdgcn_mfma_f32_16x16x32_bf16(ab[kt], bp[kt * 64], acc,
                                                      0, 0, 0);
#pragma unroll
      for (int q = 0; q < 4; ++q)
        out_pc[(R0 + r0 + ln4 * 4 + q) * NPC + colc] = acc[q];
    }
    {
      int colc = ln15;
      float bias = (colc < NHD) ? b_hd[colc] : 0.0f;
      f32x4 acc = {bias, bias, bias, bias};
      const short8* bp = (const short8*)Whd_pack + lane;
#pragma unroll
      for (int kt = 0; kt < 8; ++kt)
        acc = __builtin_amdgcn_mfma_f32_16x16x32_bf16(ab[kt], bp[kt * 64], acc,
                                                      0, 0, 0);
      if (colc < NHD) {
#pragma unroll
        for (int q = 0; q < 4; ++q)
          out_hd[(R0 + r0 + ln4 * 4 + q) * NHD + colc] = acc[q];
      }
    }
  }
}

// ---------------------------------------------------------------------------
extern "C" void kernel_launch(void* const* d_in, const int* in_sizes, int n_in,
                              void* d_out, int out_size, void* d_ws,
                              size_t ws_size, hipStream_t stream) {
  (void)in_sizes;
  (void)n_in;
  (void)out_size;
  (void)ws_size;
  const float* x = (const float*)d_in[0];
  const float* init_pc = (const float*)d_in[1];
  const float* init_hd = (const float*)d_in[2];
  const float* Wz = (const float*)d_in[3];
  const float* Wr = (const float*)d_in[4];
  const float* Wh = (const float*)d_in[5];
  const float* Uz = (const float*)d_in[6];
  const float* Ur = (const float*)d_in[7];
  const float* Uh = (const float*)d_in[8];
  const float* bz = (const float*)d_in[9];
  const float* br = (const float*)d_in[10];
  const float* bh = (const float*)d_in[11];
  const float* W_embed = (const float*)d_in[12];
  const float* b_embed = (const float*)d_in[13];
  const float* W_bneck = (const float*)d_in[14];
  const float* W_pc = (const float*)d_in[15];
  const float* b_pc = (const float*)d_in[16];
  const float* W_hd = (const float*)d_in[17];
  const float* b_hd = (const float*)d_in[18];

  float* out = (float*)d_out;
  float* out_hd = out;
  float* out_pc = out_hd + (size_t)TT * BB * NHD;
  float* out_bn = out_pc + (size_t)TT * BB * NPC;
  float* out_st = out_bn + (size_t)TT * BB * NB;
  float* out_fs = out_st + (size_t)TT * BB * NU;

  float* h0 = (float*)d_ws;                            // 1 MB
  short* Wb_pack = (short*)((char*)d_ws + (1 << 20));  // 64 KB
  short* Wpc_pack = Wb_pack + 64 * 64 * 8;             // 128 KB
  short* Whd_pack = Wpc_pack + 128 * 64 * 8;           // 8 KB
  short* gru_frags = (short*)((char*)d_ws + (1 << 20) + 200 * 1024);  // 152 KB

  prepack_kernel<<<50, 256, 0, stream>>>(W_bneck, W_pc, W_hd, Wb_pack,
                                         Wpc_pack, Whd_pack);
  prepack_gru_kernel<<<38, 256, 0, stream>>>(Uz, Ur, Uh, Wz, Wr, Wh, bz, br,
                                             bh, gru_frags);
  embed_kernel<<<BB / 2, 256, 0, stream>>>(init_pc, init_hd, W_embed, b_embed,
                                           h0);
  gru_pipe_kernel<<<BB / 4, 256, 0, stream>>>(x, h0, gru_frags, out_st,
                                              out_fs);
  heads_mfma_kernel<<<(TT * BB) / 64, 256, 0, stream>>>(
      out_st, Wb_pack, Wpc_pack, Whd_pack, b_pc, b_hd, out_hd, out_pc, out_bn);
}

// Round 10
// 414.991 us; speedup vs baseline: 2.7781x; 1.2298x over previous
//
#include <hip/hip_runtime.h>

#define TT 100
#define BB 2048
#define NI 3
#define NU 128
#define NB 256
#define NPC 256
#define NHD 12

typedef __attribute__((ext_vector_type(8))) short short8;
typedef __attribute__((ext_vector_type(4))) float f32x4;

__device__ __forceinline__ float fast_sigmoid(float x) {
  return 1.0f / (1.0f + __expf(-x));
}
__device__ __forceinline__ float fast_tanh(float x) {
  return 1.0f - 2.0f / (__expf(2.0f * x) + 1.0f);
}
__device__ __forceinline__ short f2bf(float f) {
  uint32_t u = __float_as_uint(f);
  u += 0x7FFF + ((u >> 16) & 1);  // RNE
  return (short)(u >> 16);
}
__device__ __forceinline__ float bf2f(short s) {
  return __uint_as_float(((uint32_t)(uint16_t)s) << 16);
}
// HW packed f32->bf16 (RNE), 1 instruction for 2 values.
__device__ __forceinline__ uint32_t cvt_pk_bf16(float lo, float hi) {
  uint32_t r;
  asm("v_cvt_pk_bf16_f32 %0, %1, %2" : "=v"(r) : "v"(lo), "v"(hi));
  return r;
}
// LDS-only barrier: leaves global (vmcnt) stores in flight across the barrier.
__device__ __forceinline__ void lds_barrier() {
  asm volatile("s_waitcnt lgkmcnt(0)" ::: "memory");
  __builtin_amdgcn_s_barrier();
}

// ---------------------------------------------------------------------------
// h0 = concat(init_pc, init_hd) @ W_embed + b_embed     [B, NU]
// ---------------------------------------------------------------------------
__global__ __launch_bounds__(256) void embed_kernel(
    const float* __restrict__ init_pc, const float* __restrict__ init_hd,
    const float* __restrict__ W_embed, const float* __restrict__ b_embed,
    float* __restrict__ h0) {
  __shared__ float pcs[2][NPC];
  __shared__ float hds[2][NHD];
  const int tid = threadIdx.x;
  const int b0 = blockIdx.x * 2;

  for (int idx = tid; idx < 2 * NPC; idx += 256)
    pcs[idx >> 8][idx & 255] =
        init_pc[(size_t)(b0 + (idx >> 8)) * NPC + (idx & 255)];
  if (tid < 2 * NHD) {
    int rr = tid / NHD, cc = tid - rr * NHD;
    hds[rr][cc] = init_hd[(size_t)(b0 + rr) * NHD + cc];
  }
  __syncthreads();

  const int half = tid >> 7;
  const int j = tid & 127;
  const float* Wp = W_embed + j;
  float a0 = 0.f, a1 = 0.f, a2 = 0.f, a3 = 0.f;
#pragma unroll 4
  for (int k = 0; k < NPC; k += 4) {
    a0 = fmaf(pcs[half][k + 0], Wp[(k + 0) * NU], a0);
    a1 = fmaf(pcs[half][k + 1], Wp[(k + 1) * NU], a1);
    a2 = fmaf(pcs[half][k + 2], Wp[(k + 2) * NU], a2);
    a3 = fmaf(pcs[half][k + 3], Wp[(k + 3) * NU], a3);
  }
#pragma unroll
  for (int k = 0; k < NHD; ++k)
    a0 = fmaf(hds[half][k], Wp[(NPC + k) * NU], a0);
  float acc = b_embed[j] + ((a0 + a1) + (a2 + a3));
  h0[(size_t)(b0 + half) * NU + j] = acc;
}

// ---------------------------------------------------------------------------
// Pre-pack GRU weights as bf16 MFMA B-fragments into workspace (unchanged).
//   f in [0,96):    hi of U_g, g=f>>5 (0=Uz,1=Ur,2=Uh), nt=(f>>2)&7, kt=f&3
//   f in [96,128):  lo of Uh, nt=(f>>2)&7, kt=f&3
//   f in [128,152): augmented x-proj frag: w=f-128, g=w>>3, nt=w&7,
//                   B[k][col]: k<3 -> W_g[k][col], k==3 -> bias_g[col], else 0
// ---------------------------------------------------------------------------
__global__ __launch_bounds__(256) void prepack_gru_kernel(
    const float* __restrict__ Uz, const float* __restrict__ Ur,
    const float* __restrict__ Uh, const float* __restrict__ Wz,
    const float* __restrict__ Wr, const float* __restrict__ Wh,
    const float* __restrict__ bz, const float* __restrict__ br,
    const float* __restrict__ bh, short* __restrict__ gfrags) {
  int t = blockIdx.x * 256 + threadIdx.x;
  if (t >= 152 * 64) return;
  const int f = t >> 6, lane = t & 63;
  const int ln15 = lane & 15, g4 = lane >> 4;
  short8 p;
  if (f < 128) {
    const int g = f >> 5;  // 3 for the Uh-lo band
    const int nt = (f >> 2) & 7, kt = f & 3;
    const float* U = (g == 0) ? Uz : (g == 1) ? Ur : Uh;
#pragma unroll
    for (int e = 0; e < 8; ++e) {
      const float v = U[(kt * 32 + g4 * 8 + e) * NU + nt * 16 + ln15];
      const short hi = f2bf(v);
      p[e] = (f < 96) ? hi : f2bf(v - bf2f(hi));
    }
  } else {
    const int w = f - 128;
    const int g = w >> 3, nt = w & 7;
    const float* W = (g == 0) ? Wz : (g == 1) ? Wr : Wh;
    const float* bb = (g == 0) ? bz : (g == 1) ? br : bh;
    const int col = nt * 16 + ln15;
#pragma unroll
    for (int e = 0; e < 8; ++e) {
      const int k = g4 * 8 + e;
      float v = 0.0f;
      if (k < 3) v = W[k * NU + col];
      if (k == 3) v = bb[col];
      p[e] = f2bf(v);
    }
  }
  *((short8*)gfrags + (f * 64 + lane)) = p;
}

// ---------------------------------------------------------------------------
// Lean GRU scan. 512 blocks x 4 real rows (M padded 16); 512 thr = 8 waves;
// wave w owns cols [16w,16w+16) -> U slice = 16 frags (64 VGPR).
// launch_bounds(512,4): regs capped 128 -> 16 waves/CU = 2 independent
// blocks/CU (4 waves/SIMD from 2 barrier groups).
// Precision: gates 1-term (ahi*Uhi); h-tilde 2-term (phi*Uhh + phi*Uhl) --
// B-side Uh-lo kept (systematic bias), exchanges hi-only (random rounding).
// hreg master stays fp32. cvt_pk for all bf16 packing. Pad rows of the LDS
// planes are never initialized: D rows 4-15 are discarded (row-local MFMA).
// ---------------------------------------------------------------------------
__global__ __launch_bounds__(512, 4) void gru_lean_kernel(
    const float* __restrict__ x, const float* __restrict__ h0,
    const short* __restrict__ gfrags, float* __restrict__ states,
    float* __restrict__ final_state) {
  __shared__ short h_hi[16 * 128];  // 4 KB
  __shared__ short p_hi[16 * 128];  // 4 KB
  __shared__ short8 waug[24 * 64];  // 24 KB
  __shared__ float xs[TT][4][4];    // 6.4 KB

  const int tid = threadIdx.x;
  const int lane = tid & 63;
  const int w = tid >> 6;  // 0..7
  const int ln15 = lane & 15, g4 = lane >> 4;
  const int col = w * 16 + ln15;
  const int row0 = blockIdx.x * 4;

  // ---- stage Waug fragments + x for all T ----
  for (int i = tid; i < 24 * 64; i += 512)
    waug[i] = *((const short8*)gfrags + (size_t)(128 + (i >> 6)) * 64 + (i & 63));
  for (int i = tid; i < TT * 16; i += 512) {
    const int t = i >> 4, r = (i >> 2) & 3, c = i & 3;
    ((float*)xs)[i] = (c < 3) ? x[(size_t)(t * BB + row0 + r) * NI + c] : 1.0f;
  }

  // ---- U fragments -> registers (16 frags = 64 VGPR) ----
  short8 Uzh[4], Urh[4], Uhh[4], Uhl[4];
#pragma unroll
  for (int kt = 0; kt < 4; ++kt) {
    Uzh[kt] = *((const short8*)gfrags + (size_t)(w * 4 + kt) * 64 + lane);
    Urh[kt] = *((const short8*)gfrags + (size_t)(32 + w * 4 + kt) * 64 + lane);
    Uhh[kt] = *((const short8*)gfrags + (size_t)(64 + w * 4 + kt) * 64 + lane);
    Uhl[kt] = *((const short8*)gfrags + (size_t)(96 + w * 4 + kt) * 64 + lane);
  }
#pragma unroll
  for (int kt = 0; kt < 4; ++kt) {
    asm volatile("" : "+v"(Uzh[kt]));
    asm volatile("" : "+v"(Urh[kt]));
    asm volatile("" : "+v"(Uhh[kt]));
    asm volatile("" : "+v"(Uhl[kt]));
  }

  // ---- fragment byte offsets (verified swizzle) ----
  int foff[4];
#pragma unroll
  for (int kt = 0; kt < 4; ++kt)
    foff[kt] = ln15 * 256 + ((kt * 64 + g4 * 16) ^ ((ln15 & 7) << 4));
  int woff[4];
#pragma unroll
  for (int q = 0; q < 4; ++q)
    woff[q] = q * 256 + ((col * 2) ^ ((q & 7) << 4));

  // ---- init h (rows 0-3 real; pad rows never touched) ----
  float hreg[4] = {0.f, 0.f, 0.f, 0.f};
  if (g4 == 0) {
#pragma unroll
    for (int q = 0; q < 4; ++q)
      hreg[q] = h0[(size_t)(row0 + q) * NU + col];
    const uint32_t pk01 = cvt_pk_bf16(hreg[0], hreg[1]);
    const uint32_t pk23 = cvt_pk_bf16(hreg[2], hreg[3]);
    *(short*)((char*)h_hi + woff[0]) = (short)pk01;
    *(short*)((char*)h_hi + woff[1]) = (short)(pk01 >> 16);
    *(short*)((char*)h_hi + woff[2]) = (short)pk23;
    *(short*)((char*)h_hi + woff[3]) = (short)(pk23 >> 16);
  }
  __syncthreads();

  const f32x4 zero = {0.f, 0.f, 0.f, 0.f};
  float* states_base = states + (size_t)row0 * NU + col;

  for (int t = 0; t < TT; ++t) {
    // ---- h A-fragments + augmented x fragment ----
    short8 ahi[4];
#pragma unroll
    for (int kt = 0; kt < 4; ++kt)
      ahi[kt] = *(const short8*)((const char*)h_hi + foff[kt]);
    short8 ax = {0, 0, 0, 0, 0, 0, 0, 0};
    {
      const float4 xv = *(const float4*)&xs[t][ln15 & 3][0];
      if (g4 == 0) {
        const uint32_t a = cvt_pk_bf16(xv.x, xv.y);
        const uint32_t b = cvt_pk_bf16(xv.z, xv.w);  // xv.w = 1.0 (bias row)
        ax[0] = (short)a;
        ax[1] = (short)(a >> 16);
        ax[2] = (short)b;
        ax[3] = (short)(b >> 16);
      }
    }

    // ================= phase A: z and r gates (1-term) =================
    f32x4 zacc = __builtin_amdgcn_mfma_f32_16x16x32_bf16(
        ax, waug[0 * 8 * 64 + w * 64 + lane], zero, 0, 0, 0);
    f32x4 racc = __builtin_amdgcn_mfma_f32_16x16x32_bf16(
        ax, waug[1 * 8 * 64 + w * 64 + lane], zero, 0, 0, 0);
#pragma unroll
    for (int kt = 0; kt < 4; ++kt) {
      zacc = __builtin_amdgcn_mfma_f32_16x16x32_bf16(ahi[kt], Uzh[kt], zacc, 0, 0, 0);
      racc = __builtin_amdgcn_mfma_f32_16x16x32_bf16(ahi[kt], Urh[kt], racc, 0, 0, 0);
    }

    float zg[4];
#pragma unroll
    for (int q = 0; q < 4; ++q) zg[q] = fast_sigmoid(zacc[q]);
    if (g4 == 0) {
      float rh[4];
#pragma unroll
      for (int q = 0; q < 4; ++q)
        rh[q] = fast_sigmoid(racc[q]) * hreg[q];
      const uint32_t pk01 = cvt_pk_bf16(rh[0], rh[1]);
      const uint32_t pk23 = cvt_pk_bf16(rh[2], rh[3]);
      *(short*)((char*)p_hi + woff[0]) = (short)pk01;
      *(short*)((char*)p_hi + woff[1]) = (short)(pk01 >> 16);
      *(short*)((char*)p_hi + woff[2]) = (short)pk23;
      *(short*)((char*)p_hi + woff[3]) = (short)(pk23 >> 16);
    }
    lds_barrier();  // rh plane visible

    // ============ phase B: h-tilde (phi*Uhh + phi*Uhl) + update ============
    short8 phi[4];
#pragma unroll
    for (int kt = 0; kt < 4; ++kt)
      phi[kt] = *(const short8*)((const char*)p_hi + foff[kt]);
    f32x4 hacc = __builtin_amdgcn_mfma_f32_16x16x32_bf16(
        ax, waug[2 * 8 * 64 + w * 64 + lane], zero, 0, 0, 0);
    f32x4 hacc2 = zero;
#pragma unroll
    for (int kt = 0; kt < 4; ++kt) {
      hacc = __builtin_amdgcn_mfma_f32_16x16x32_bf16(phi[kt], Uhh[kt], hacc, 0, 0, 0);
      hacc2 = __builtin_amdgcn_mfma_f32_16x16x32_bf16(phi[kt], Uhl[kt], hacc2, 0, 0, 0);
    }
#pragma unroll
    for (int q = 0; q < 4; ++q) {
      const float htw = fast_tanh(hacc[q] + hacc2[q]);
      hreg[q] = fmaf(zg[q], htw - hreg[q], hreg[q]);
    }
    if (g4 == 0) {
      const uint32_t pk01 = cvt_pk_bf16(hreg[0], hreg[1]);
      const uint32_t pk23 = cvt_pk_bf16(hreg[2], hreg[3]);
      *(short*)((char*)h_hi + woff[0]) = (short)pk01;
      *(short*)((char*)h_hi + woff[1]) = (short)(pk01 >> 16);
      *(short*)((char*)h_hi + woff[2]) = (short)pk23;
      *(short*)((char*)h_hi + woff[3]) = (short)(pk23 >> 16);
      // fire-and-forget HBM stores (no vmcnt wait in loop)
      float* sp = states_base + (size_t)t * BB * NU;
#pragma unroll
      for (int q = 0; q < 4; ++q) sp[q * NU] = hreg[q];
    }
    lds_barrier();  // h plane visible
  }

  if (g4 == 0) {
#pragma unroll
    for (int q = 0; q < 4; ++q)
      final_state[(size_t)(row0 + q) * NU + col] = hreg[q];
  }
}

// ---------------------------------------------------------------------------
// Pre-pack heads weights into bf16 MFMA B-fragment order (unchanged).
// ---------------------------------------------------------------------------
__global__ __launch_bounds__(256) void prepack_kernel(
    const float* __restrict__ Wb, const float* __restrict__ Wpc,
    const float* __restrict__ Whd, short* __restrict__ Wb_pack,
    short* __restrict__ Wpc_pack, short* __restrict__ Whd_pack) {
  int t = blockIdx.x * 256 + threadIdx.x;
  if (t >= 200 * 64) return;
  int fb = t >> 6, lane = t & 63;
  const float* W;
  short* out;
  int n_tile, k_tile, N, local;
  if (fb < 64) {
    W = Wb; out = Wb_pack; local = fb; n_tile = fb >> 2; k_tile = fb & 3; N = 256;
  } else if (fb < 192) {
    int f = fb - 64;
    W = Wpc; out = Wpc_pack; local = f; n_tile = f >> 3; k_tile = f & 7; N = 256;
  } else {
    int f = fb - 192;
    W = Whd; out = Whd_pack; local = f; n_tile = 0; k_tile = f; N = 12;
  }
  short8 p;
#pragma unroll
  for (int e = 0; e < 8; ++e) {
    int k = k_tile * 32 + (lane >> 4) * 8 + e;
    int colc = n_tile * 16 + (lane & 15);
    float v = (colc < N) ? W[k * N + colc] : 0.0f;
    p[e] = f2bf(v);
  }
  *((short8*)out + (local * 64 + lane)) = p;
}

// ---------------------------------------------------------------------------
// MFMA heads: 64 rows/block, 256 threads (4 waves, 16-row stripe each).
// ---------------------------------------------------------------------------
__global__ __launch_bounds__(256, 3) void heads_mfma_kernel(
    const float* __restrict__ states, const short* __restrict__ Wb_pack,
    const short* __restrict__ Wpc_pack, const short* __restrict__ Whd_pack,
    const float* __restrict__ b_pc, const float* __restrict__ b_hd,
    float* __restrict__ out_hd, float* __restrict__ out_pc,
    float* __restrict__ out_bn) {
  __shared__ short s_lds[64 * 128];   // 16 KB
  __shared__ short bn_lds[64 * 256];  // 32 KB
  const int tid = threadIdx.x;
  const size_t R0 = (size_t)blockIdx.x * 64;

  for (int c = tid; c < 1024; c += 256) {
    int row = c >> 4, s16 = c & 15;
    const float* src = states + (R0 + row) * 128 + s16 * 8;
    float4 v0 = *(const float4*)src;
    float4 v1 = *(const float4*)(src + 4);
    short8 p;
    p[0] = f2bf(v0.x); p[1] = f2bf(v0.y); p[2] = f2bf(v0.z); p[3] = f2bf(v0.w);
    p[4] = f2bf(v1.x); p[5] = f2bf(v1.y); p[6] = f2bf(v1.z); p[7] = f2bf(v1.w);
    int byte = row * 256 + ((s16 * 16) ^ ((row & 7) << 4));
    *(short8*)((char*)s_lds + byte) = p;
  }
  __syncthreads();

  const int lane = tid & 63;
  const int wave = tid >> 6;
  const int ln15 = lane & 15;
  const int ln4 = lane >> 4;
  const int r0 = wave * 16;

  {
    short8 a[4];
#pragma unroll
    for (int kt = 0; kt < 4; ++kt) {
      int byte =
          (r0 + ln15) * 256 + ((kt * 64 + ln4 * 16) ^ ((ln15 & 7) << 4));
      a[kt] = *(const short8*)((const char*)s_lds + byte);
    }
#pragma unroll
    for (int nt = 0; nt < 16; ++nt) {
      f32x4 acc = {0.f, 0.f, 0.f, 0.f};
      const short8* bp = (const short8*)Wb_pack + (nt * 4) * 64 + lane;
#pragma unroll
      for (int kt = 0; kt < 4; ++kt)
        acc = __builtin_amdgcn_mfma_f32_16x16x32_bf16(a[kt], bp[kt * 64], acc,
                                                      0, 0, 0);
      int colc = nt * 16 + ln15;
#pragma unroll
      for (int q = 0; q < 4; ++q) {
        int row = r0 + ln4 * 4 + q;
        out_bn[(R0 + row) * NB + colc] = acc[q];
        int byte = row * 512 + ((colc * 2) ^ ((row & 7) << 4));
        *(short*)((char*)bn_lds + byte) = f2bf(acc[q]);
      }
    }
  }
  __syncthreads();

  {
    short8 ab[8];
#pragma unroll
    for (int kt = 0; kt < 8; ++kt) {
      int byte =
          (r0 + ln15) * 512 + ((kt * 64 + ln4 * 16) ^ ((ln15 & 7) << 4));
      ab[kt] = *(const short8*)((const char*)bn_lds + byte);
    }
#pragma unroll
    for (int nt = 0; nt < 16; ++nt) {
      int colc = nt * 16 + ln15;
      float bias = b_pc[colc];
      f32x4 acc = {bias, bias, bias, bias};
      const short8* bp = (const short8*)Wpc_pack + (nt * 8) * 64 + lane;
#pragma unroll
      for (int kt = 0; kt < 8; ++kt)
        acc = __builtin_amdgcn_mfma_f32_16x16x32_bf16(ab[kt], bp[kt * 64], acc,
                                                      0, 0, 0);
#pragma unroll
      for (int q = 0; q < 4; ++q)
        out_pc[(R0 + r0 + ln4 * 4 + q) * NPC + colc] = acc[q];
    }
    {
      int colc = ln15;
      float bias = (colc < NHD) ? b_hd[colc] : 0.0f;
      f32x4 acc = {bias, bias, bias, bias};
      const short8* bp = (const short8*)Whd_pack + lane;
#pragma unroll
      for (int kt = 0; kt < 8; ++kt)
        acc = __builtin_amdgcn_mfma_f32_16x16x32_bf16(ab[kt], bp[kt * 64], acc,
                                                      0, 0, 0);
      if (colc < NHD) {
#pragma unroll
        for (int q = 0; q < 4; ++q)
          out_hd[(R0 + r0 + ln4 * 4 + q) * NHD + colc] = acc[q];
      }
    }
  }
}

// ---------------------------------------------------------------------------
extern "C" void kernel_launch(void* const* d_in, const int* in_sizes, int n_in,
                              void* d_out, int out_size, void* d_ws,
                              size_t ws_size, hipStream_t stream) {
  (void)in_sizes;
  (void)n_in;
  (void)out_size;
  (void)ws_size;
  const float* x = (const float*)d_in[0];
  const float* init_pc = (const float*)d_in[1];
  const float* init_hd = (const float*)d_in[2];
  const float* Wz = (const float*)d_in[3];
  const float* Wr = (const float*)d_in[4];
  const float* Wh = (const float*)d_in[5];
  const float* Uz = (const float*)d_in[6];
  const float* Ur = (const float*)d_in[7];
  const float* Uh = (const float*)d_in[8];
  const float* bz = (const float*)d_in[9];
  const float* br = (const float*)d_in[10];
  const float* bh = (const float*)d_in[11];
  const float* W_embed = (const float*)d_in[12];
  const float* b_embed = (const float*)d_in[13];
  const float* W_bneck = (const float*)d_in[14];
  const float* W_pc = (const float*)d_in[15];
  const float* b_pc = (const float*)d_in[16];
  const float* W_hd = (const float*)d_in[17];
  const float* b_hd = (const float*)d_in[18];

  float* out = (float*)d_out;
  float* out_hd = out;
  float* out_pc = out_hd + (size_t)TT * BB * NHD;
  float* out_bn = out_pc + (size_t)TT * BB * NPC;
  float* out_st = out_bn + (size_t)TT * BB * NB;
  float* out_fs = out_st + (size_t)TT * BB * NU;

  float* h0 = (float*)d_ws;                            // 1 MB
  short* Wb_pack = (short*)((char*)d_ws + (1 << 20));  // 64 KB
  short* Wpc_pack = Wb_pack + 64 * 64 * 8;             // 128 KB
  short* Whd_pack = Wpc_pack + 128 * 64 * 8;           // 8 KB
  short* gru_frags = (short*)((char*)d_ws + (1 << 20) + 200 * 1024);  // 152 KB

  prepack_kernel<<<50, 256, 0, stream>>>(W_bneck, W_pc, W_hd, Wb_pack,
                                         Wpc_pack, Whd_pack);
  prepack_gru_kernel<<<38, 256, 0, stream>>>(Uz, Ur, Uh, Wz, Wr, Wh, bz, br,
                                             bh, gru_frags);
  embed_kernel<<<BB / 2, 256, 0, stream>>>(init_pc, init_hd, W_embed, b_embed,
                                           h0);
  gru_lean_kernel<<<BB / 4, 512, 0, stream>>>(x, h0, gru_frags, out_st,
                                              out_fs);
  heads_mfma_kernel<<<(TT * BB) / 64, 256, 0, stream>>>(
      out_st, Wb_pack, Wpc_pack, Whd_pack, b_pc, b_hd, out_hd, out_pc, out_bn);
}

// Round 11
// 319.599 us; speedup vs baseline: 3.6073x; 1.2985x over previous
//
#include <hip/hip_runtime.h>

#define TT 100
#define BB 2048
#define NI 3
#define NU 128
#define NB 256
#define NPC 256
#define NHD 12

typedef __attribute__((ext_vector_type(8))) short short8;
typedef __attribute__((ext_vector_type(4))) float f32x4;

__device__ __forceinline__ float fast_sigmoid(float x) {
  return 1.0f / (1.0f + __expf(-x));
}
__device__ __forceinline__ float fast_tanh(float x) {
  return 1.0f - 2.0f / (__expf(2.0f * x) + 1.0f);
}
__device__ __forceinline__ short f2bf(float f) {
  uint32_t u = __float_as_uint(f);
  u += 0x7FFF + ((u >> 16) & 1);  // RNE
  return (short)(u >> 16);
}
__device__ __forceinline__ float bf2f(short s) {
  return __uint_as_float(((uint32_t)(uint16_t)s) << 16);
}
// HW packed f32->bf16 (RNE), 1 instruction for 2 values.
__device__ __forceinline__ uint32_t cvt_pk_bf16(float lo, float hi) {
  uint32_t r;
  asm("v_cvt_pk_bf16_f32 %0, %1, %2" : "=v"(r) : "v"(lo), "v"(hi));
  return r;
}
// LDS-only barrier: leaves global (vmcnt) stores in flight across the barrier.
__device__ __forceinline__ void lds_barrier() {
  asm volatile("s_waitcnt lgkmcnt(0)" ::: "memory");
  __builtin_amdgcn_s_barrier();
}

// ---------------------------------------------------------------------------
// h0 = concat(init_pc, init_hd) @ W_embed + b_embed     [B, NU]
// ---------------------------------------------------------------------------
__global__ __launch_bounds__(256) void embed_kernel(
    const float* __restrict__ init_pc, const float* __restrict__ init_hd,
    const float* __restrict__ W_embed, const float* __restrict__ b_embed,
    float* __restrict__ h0) {
  __shared__ float pcs[2][NPC];
  __shared__ float hds[2][NHD];
  const int tid = threadIdx.x;
  const int b0 = blockIdx.x * 2;

  for (int idx = tid; idx < 2 * NPC; idx += 256)
    pcs[idx >> 8][idx & 255] =
        init_pc[(size_t)(b0 + (idx >> 8)) * NPC + (idx & 255)];
  if (tid < 2 * NHD) {
    int rr = tid / NHD, cc = tid - rr * NHD;
    hds[rr][cc] = init_hd[(size_t)(b0 + rr) * NHD + cc];
  }
  __syncthreads();

  const int half = tid >> 7;
  const int j = tid & 127;
  const float* Wp = W_embed + j;
  float a0 = 0.f, a1 = 0.f, a2 = 0.f, a3 = 0.f;
#pragma unroll 4
  for (int k = 0; k < NPC; k += 4) {
    a0 = fmaf(pcs[half][k + 0], Wp[(k + 0) * NU], a0);
    a1 = fmaf(pcs[half][k + 1], Wp[(k + 1) * NU], a1);
    a2 = fmaf(pcs[half][k + 2], Wp[(k + 2) * NU], a2);
    a3 = fmaf(pcs[half][k + 3], Wp[(k + 3) * NU], a3);
  }
#pragma unroll
  for (int k = 0; k < NHD; ++k)
    a0 = fmaf(hds[half][k], Wp[(NPC + k) * NU], a0);
  float acc = b_embed[j] + ((a0 + a1) + (a2 + a3));
  h0[(size_t)(b0 + half) * NU + j] = acc;
}

// ---------------------------------------------------------------------------
// Pre-pack GRU weights as bf16 MFMA B-fragments into workspace (unchanged).
//   f in [0,96):    hi of U_g, g=f>>5 (0=Uz,1=Ur,2=Uh), nt=(f>>2)&7, kt=f&3
//   f in [96,128):  lo of Uh, nt=(f>>2)&7, kt=f&3
//   f in [128,152): augmented x-proj frag: w=f-128, g=w>>3, nt=w&7,
//                   B[k][col]: k<3 -> W_g[k][col], k==3 -> bias_g[col], else 0
// ---------------------------------------------------------------------------
__global__ __launch_bounds__(256) void prepack_gru_kernel(
    const float* __restrict__ Uz, const float* __restrict__ Ur,
    const float* __restrict__ Uh, const float* __restrict__ Wz,
    const float* __restrict__ Wr, const float* __restrict__ Wh,
    const float* __restrict__ bz, const float* __restrict__ br,
    const float* __restrict__ bh, short* __restrict__ gfrags) {
  int t = blockIdx.x * 256 + threadIdx.x;
  if (t >= 152 * 64) return;
  const int f = t >> 6, lane = t & 63;
  const int ln15 = lane & 15, g4 = lane >> 4;
  short8 p;
  if (f < 128) {
    const int g = f >> 5;  // 3 for the Uh-lo band
    const int nt = (f >> 2) & 7, kt = f & 3;
    const float* U = (g == 0) ? Uz : (g == 1) ? Ur : Uh;
#pragma unroll
    for (int e = 0; e < 8; ++e) {
      const float v = U[(kt * 32 + g4 * 8 + e) * NU + nt * 16 + ln15];
      const short hi = f2bf(v);
      p[e] = (f < 96) ? hi : f2bf(v - bf2f(hi));
    }
  } else {
    const int w = f - 128;
    const int g = w >> 3, nt = w & 7;
    const float* W = (g == 0) ? Wz : (g == 1) ? Wr : Wh;
    const float* bb = (g == 0) ? bz : (g == 1) ? br : bh;
    const int col = nt * 16 + ln15;
#pragma unroll
    for (int e = 0; e < 8; ++e) {
      const int k = g4 * 8 + e;
      float v = 0.0f;
      if (k < 3) v = W[k * NU + col];
      if (k == 3) v = bb[col];
      p[e] = f2bf(v);
    }
  }
  *((short8*)gfrags + (f * 64 + lane)) = p;
}

// ---------------------------------------------------------------------------
// GRU scan: R4's row-efficient skeleton + R10's lean payload.
// 256 blocks x 8 REAL rows (M padded 16); 512 thr = 8 waves; wave w owns
// cols [16w,16w+16) -> U slice = 16 frags (64 VGPR).
// Per wave per step: 8 ds_read_b128 (hi-only h/p planes), 19 MFMA
// (gates 1-term, h-tilde 2-term with B-side Uh-lo), x-proj folded into
// MFMA via augmented-K waug frags, cvt_pk packing, fire-and-forget stores.
// Pad rows 8-15 of the planes are never written: garbage A-rows only
// produce garbage D-rows 8-15, which are discarded (row-local MFMA).
// ---------------------------------------------------------------------------
__global__ __launch_bounds__(512, 2) void gru_fast_kernel(
    const float* __restrict__ x, const float* __restrict__ h0,
    const short* __restrict__ gfrags, float* __restrict__ states,
    float* __restrict__ final_state) {
  __shared__ short h_hi[16 * 128];  // 4 KB (rows 8-15 uninitialized pad)
  __shared__ short p_hi[16 * 128];  // 4 KB
  __shared__ short8 waug[24 * 64];  // 24 KB
  __shared__ float xs[TT][8][4];    // 12.8 KB, [r][3] = 1.0 (bias row)

  const int tid = threadIdx.x;
  const int lane = tid & 63;
  const int w = tid >> 6;  // 0..7 == nt
  const int ln15 = lane & 15, g4 = lane >> 4;
  const int col = w * 16 + ln15;
  const int row0 = blockIdx.x * 8;

  // ---- stage Waug fragments + x for all T ----
  for (int i = tid; i < 24 * 64; i += 512)
    waug[i] = *((const short8*)gfrags + (size_t)(128 + (i >> 6)) * 64 + (i & 63));
  for (int i = tid; i < TT * 32; i += 512) {
    const int t = i >> 5, r = (i >> 2) & 7, c = i & 3;
    ((float*)xs)[i] = (c < 3) ? x[(size_t)(t * BB + row0 + r) * NI + c] : 1.0f;
  }

  // ---- U fragments -> registers (16 frags = 64 VGPR) ----
  short8 Uzh[4], Urh[4], Uhh[4], Uhl[4];
#pragma unroll
  for (int kt = 0; kt < 4; ++kt) {
    Uzh[kt] = *((const short8*)gfrags + (size_t)(w * 4 + kt) * 64 + lane);
    Urh[kt] = *((const short8*)gfrags + (size_t)(32 + w * 4 + kt) * 64 + lane);
    Uhh[kt] = *((const short8*)gfrags + (size_t)(64 + w * 4 + kt) * 64 + lane);
    Uhl[kt] = *((const short8*)gfrags + (size_t)(96 + w * 4 + kt) * 64 + lane);
  }

  // ---- fragment byte offsets (verified swizzle) ----
  int foff[4];
#pragma unroll
  for (int kt = 0; kt < 4; ++kt)
    foff[kt] = ln15 * 256 + ((kt * 64 + g4 * 16) ^ ((ln15 & 7) << 4));
  int woff[4];  // valid for g4 < 2: rows 0-7
#pragma unroll
  for (int q = 0; q < 4; ++q) {
    const int row = g4 * 4 + q;
    woff[q] = (row & 7) * 256 + ((col * 2) ^ ((row & 7) << 4));
  }

  // ---- init h (rows 0-7 real; pad rows untouched) ----
  float hreg[4] = {0.f, 0.f, 0.f, 0.f};
  if (g4 < 2) {
#pragma unroll
    for (int q = 0; q < 4; ++q)
      hreg[q] = h0[(size_t)(row0 + g4 * 4 + q) * NU + col];
    const uint32_t pk01 = cvt_pk_bf16(hreg[0], hreg[1]);
    const uint32_t pk23 = cvt_pk_bf16(hreg[2], hreg[3]);
    *(short*)((char*)h_hi + woff[0]) = (short)pk01;
    *(short*)((char*)h_hi + woff[1]) = (short)(pk01 >> 16);
    *(short*)((char*)h_hi + woff[2]) = (short)pk23;
    *(short*)((char*)h_hi + woff[3]) = (short)(pk23 >> 16);
  }
  __syncthreads();

  const f32x4 zero = {0.f, 0.f, 0.f, 0.f};

  for (int t = 0; t < TT; ++t) {
    // ---- h A-fragments + augmented x fragment ----
    short8 ahi[4];
#pragma unroll
    for (int kt = 0; kt < 4; ++kt)
      ahi[kt] = *(const short8*)((const char*)h_hi + foff[kt]);
    short8 ax = {0, 0, 0, 0, 0, 0, 0, 0};
    {
      // A row ln15: rows 8-15 read row&7 (garbage D rows discarded anyway)
      const float4 xv = *(const float4*)&xs[t][ln15 & 7][0];
      if (g4 == 0) {
        const uint32_t a = cvt_pk_bf16(xv.x, xv.y);
        const uint32_t b = cvt_pk_bf16(xv.z, xv.w);  // xv.w = 1.0 (bias row)
        ax[0] = (short)a;
        ax[1] = (short)(a >> 16);
        ax[2] = (short)b;
        ax[3] = (short)(b >> 16);
      }
    }

    // ================= phase A: z and r gates (1-term) =================
    f32x4 zacc = __builtin_amdgcn_mfma_f32_16x16x32_bf16(
        ax, waug[(0 * 8 + w) * 64 + lane], zero, 0, 0, 0);
    f32x4 racc = __builtin_amdgcn_mfma_f32_16x16x32_bf16(
        ax, waug[(1 * 8 + w) * 64 + lane], zero, 0, 0, 0);
#pragma unroll
    for (int kt = 0; kt < 4; ++kt) {
      zacc = __builtin_amdgcn_mfma_f32_16x16x32_bf16(ahi[kt], Uzh[kt], zacc, 0, 0, 0);
      racc = __builtin_amdgcn_mfma_f32_16x16x32_bf16(ahi[kt], Urh[kt], racc, 0, 0, 0);
    }

    float zg[4];
#pragma unroll
    for (int q = 0; q < 4; ++q) zg[q] = fast_sigmoid(zacc[q]);
    if (g4 < 2) {
      float rh[4];
#pragma unroll
      for (int q = 0; q < 4; ++q) rh[q] = fast_sigmoid(racc[q]) * hreg[q];
      const uint32_t pk01 = cvt_pk_bf16(rh[0], rh[1]);
      const uint32_t pk23 = cvt_pk_bf16(rh[2], rh[3]);
      *(short*)((char*)p_hi + woff[0]) = (short)pk01;
      *(short*)((char*)p_hi + woff[1]) = (short)(pk01 >> 16);
      *(short*)((char*)p_hi + woff[2]) = (short)pk23;
      *(short*)((char*)p_hi + woff[3]) = (short)(pk23 >> 16);
    }
    lds_barrier();  // rh plane visible

    // ============ phase B: h-tilde (phi*Uhh + phi*Uhl) + update ============
    short8 phi[4];
#pragma unroll
    for (int kt = 0; kt < 4; ++kt)
      phi[kt] = *(const short8*)((const char*)p_hi + foff[kt]);
    f32x4 hacc = __builtin_amdgcn_mfma_f32_16x16x32_bf16(
        ax, waug[(2 * 8 + w) * 64 + lane], zero, 0, 0, 0);
    f32x4 hacc2 = zero;
#pragma unroll
    for (int kt = 0; kt < 4; ++kt) {
      hacc = __builtin_amdgcn_mfma_f32_16x16x32_bf16(phi[kt], Uhh[kt], hacc, 0, 0, 0);
      hacc2 = __builtin_amdgcn_mfma_f32_16x16x32_bf16(phi[kt], Uhl[kt], hacc2, 0, 0, 0);
    }
#pragma unroll
    for (int q = 0; q < 4; ++q) {
      const float htw = fast_tanh(hacc[q] + hacc2[q]);
      hreg[q] = fmaf(zg[q], htw - hreg[q], hreg[q]);
    }
    if (g4 < 2) {
      const uint32_t pk01 = cvt_pk_bf16(hreg[0], hreg[1]);
      const uint32_t pk23 = cvt_pk_bf16(hreg[2], hreg[3]);
      *(short*)((char*)h_hi + woff[0]) = (short)pk01;
      *(short*)((char*)h_hi + woff[1]) = (short)(pk01 >> 16);
      *(short*)((char*)h_hi + woff[2]) = (short)pk23;
      *(short*)((char*)h_hi + woff[3]) = (short)(pk23 >> 16);
      // fire-and-forget HBM stores (no vmcnt wait in loop)
      float* sp = states + ((size_t)t * BB + row0 + g4 * 4) * NU + col;
#pragma unroll
      for (int q = 0; q < 4; ++q) sp[q * NU] = hreg[q];
    }
    lds_barrier();  // h plane visible
  }

  if (g4 < 2) {
#pragma unroll
    for (int q = 0; q < 4; ++q)
      final_state[(size_t)(row0 + g4 * 4 + q) * NU + col] = hreg[q];
  }
}

// ---------------------------------------------------------------------------
// Pre-pack heads weights into bf16 MFMA B-fragment order (unchanged).
// ---------------------------------------------------------------------------
__global__ __launch_bounds__(256) void prepack_kernel(
    const float* __restrict__ Wb, const float* __restrict__ Wpc,
    const float* __restrict__ Whd, short* __restrict__ Wb_pack,
    short* __restrict__ Wpc_pack, short* __restrict__ Whd_pack) {
  int t = blockIdx.x * 256 + threadIdx.x;
  if (t >= 200 * 64) return;
  int fb = t >> 6, lane = t & 63;
  const float* W;
  short* out;
  int n_tile, k_tile, N, local;
  if (fb < 64) {
    W = Wb; out = Wb_pack; local = fb; n_tile = fb >> 2; k_tile = fb & 3; N = 256;
  } else if (fb < 192) {
    int f = fb - 64;
    W = Wpc; out = Wpc_pack; local = f; n_tile = f >> 3; k_tile = f & 7; N = 256;
  } else {
    int f = fb - 192;
    W = Whd; out = Whd_pack; local = f; n_tile = 0; k_tile = f; N = 12;
  }
  short8 p;
#pragma unroll
  for (int e = 0; e < 8; ++e) {
    int k = k_tile * 32 + (lane >> 4) * 8 + e;
    int colc = n_tile * 16 + (lane & 15);
    float v = (colc < N) ? W[k * N + colc] : 0.0f;
    p[e] = f2bf(v);
  }
  *((short8*)out + (local * 64 + lane)) = p;
}

// ---------------------------------------------------------------------------
// MFMA heads: 64 rows/block, 256 threads (4 waves, 16-row stripe each).
// ---------------------------------------------------------------------------
__global__ __launch_bounds__(256, 3) void heads_mfma_kernel(
    const float* __restrict__ states, const short* __restrict__ Wb_pack,
    const short* __restrict__ Wpc_pack, const short* __restrict__ Whd_pack,
    const float* __restrict__ b_pc, const float* __restrict__ b_hd,
    float* __restrict__ out_hd, float* __restrict__ out_pc,
    float* __restrict__ out_bn) {
  __shared__ short s_lds[64 * 128];   // 16 KB
  __shared__ short bn_lds[64 * 256];  // 32 KB
  const int tid = threadIdx.x;
  const size_t R0 = (size_t)blockIdx.x * 64;

  for (int c = tid; c < 1024; c += 256) {
    int row = c >> 4, s16 = c & 15;
    const float* src = states + (R0 + row) * 128 + s16 * 8;
    float4 v0 = *(const float4*)src;
    float4 v1 = *(const float4*)(src + 4);
    short8 p;
    p[0] = f2bf(v0.x); p[1] = f2bf(v0.y); p[2] = f2bf(v0.z); p[3] = f2bf(v0.w);
    p[4] = f2bf(v1.x); p[5] = f2bf(v1.y); p[6] = f2bf(v1.z); p[7] = f2bf(v1.w);
    int byte = row * 256 + ((s16 * 16) ^ ((row & 7) << 4));
    *(short8*)((char*)s_lds + byte) = p;
  }
  __syncthreads();

  const int lane = tid & 63;
  const int wave = tid >> 6;
  const int ln15 = lane & 15;
  const int ln4 = lane >> 4;
  const int r0 = wave * 16;

  {
    short8 a[4];
#pragma unroll
    for (int kt = 0; kt < 4; ++kt) {
      int byte =
          (r0 + ln15) * 256 + ((kt * 64 + ln4 * 16) ^ ((ln15 & 7) << 4));
      a[kt] = *(const short8*)((const char*)s_lds + byte);
    }
#pragma unroll
    for (int nt = 0; nt < 16; ++nt) {
      f32x4 acc = {0.f, 0.f, 0.f, 0.f};
      const short8* bp = (const short8*)Wb_pack + (nt * 4) * 64 + lane;
#pragma unroll
      for (int kt = 0; kt < 4; ++kt)
        acc = __builtin_amdgcn_mfma_f32_16x16x32_bf16(a[kt], bp[kt * 64], acc,
                                                      0, 0, 0);
      int colc = nt * 16 + ln15;
#pragma unroll
      for (int q = 0; q < 4; ++q) {
        int row = r0 + ln4 * 4 + q;
        out_bn[(R0 + row) * NB + colc] = acc[q];
        int byte = row * 512 + ((colc * 2) ^ ((row & 7) << 4));
        *(short*)((char*)bn_lds + byte) = f2bf(acc[q]);
      }
    }
  }
  __syncthreads();

  {
    short8 ab[8];
#pragma unroll
    for (int kt = 0; kt < 8; ++kt) {
      int byte =
          (r0 + ln15) * 512 + ((kt * 64 + ln4 * 16) ^ ((ln15 & 7) << 4));
      ab[kt] = *(const short8*)((const char*)bn_lds + byte);
    }
#pragma unroll
    for (int nt = 0; nt < 16; ++nt) {
      int colc = nt * 16 + ln15;
      float bias = b_pc[colc];
      f32x4 acc = {bias, bias, bias, bias};
      const short8* bp = (const short8*)Wpc_pack + (nt * 8) * 64 + lane;
#pragma unroll
      for (int kt = 0; kt < 8; ++kt)
        acc = __builtin_amdgcn_mfma_f32_16x16x32_bf16(ab[kt], bp[kt * 64], acc,
                                                      0, 0, 0);
#pragma unroll
      for (int q = 0; q < 4; ++q)
        out_pc[(R0 + r0 + ln4 * 4 + q) * NPC + colc] = acc[q];
    }
    {
      int colc = ln15;
      float bias = (colc < NHD) ? b_hd[colc] : 0.0f;
      f32x4 acc = {bias, bias, bias, bias};
      const short8* bp = (const short8*)Whd_pack + lane;
#pragma unroll
      for (int kt = 0; kt < 8; ++kt)
        acc = __builtin_amdgcn_mfma_f32_16x16x32_bf16(ab[kt], bp[kt * 64], acc,
                                                      0, 0, 0);
      if (colc < NHD) {
#pragma unroll
        for (int q = 0; q < 4; ++q)
          out_hd[(R0 + r0 + ln4 * 4 + q) * NHD + colc] = acc[q];
      }
    }
  }
}

// ---------------------------------------------------------------------------
extern "C" void kernel_launch(void* const* d_in, const int* in_sizes, int n_in,
                              void* d_out, int out_size, void* d_ws,
                              size_t ws_size, hipStream_t stream) {
  (void)in_sizes;
  (void)n_in;
  (void)out_size;
  (void)ws_size;
  const float* x = (const float*)d_in[0];
  const float* init_pc = (const float*)d_in[1];
  const float* init_hd = (const float*)d_in[2];
  const float* Wz = (const float*)d_in[3];
  const float* Wr = (const float*)d_in[4];
  const float* Wh = (const float*)d_in[5];
  const float* Uz = (const float*)d_in[6];
  const float* Ur = (const float*)d_in[7];
  const float* Uh = (const float*)d_in[8];
  const float* bz = (const float*)d_in[9];
  const float* br = (const float*)d_in[10];
  const float* bh = (const float*)d_in[11];
  const float* W_embed = (const float*)d_in[12];
  const float* b_embed = (const float*)d_in[13];
  const float* W_bneck = (const float*)d_in[14];
  const float* W_pc = (const float*)d_in[15];
  const float* b_pc = (const float*)d_in[16];
  const float* W_hd = (const float*)d_in[17];
  const float* b_hd = (const float*)d_in[18];

  float* out = (float*)d_out;
  float* out_hd = out;
  float* out_pc = out_hd + (size_t)TT * BB * NHD;
  float* out_bn = out_pc + (size_t)TT * BB * NPC;
  float* out_st = out_bn + (size_t)TT * BB * NB;
  float* out_fs = out_st + (size_t)TT * BB * NU;

  float* h0 = (float*)d_ws;                            // 1 MB
  short* Wb_pack = (short*)((char*)d_ws + (1 << 20));  // 64 KB
  short* Wpc_pack = Wb_pack + 64 * 64 * 8;             // 128 KB
  short* Whd_pack = Wpc_pack + 128 * 64 * 8;           // 8 KB
  short* gru_frags = (short*)((char*)d_ws + (1 << 20) + 200 * 1024);  // 152 KB

  prepack_kernel<<<50, 256, 0, stream>>>(W_bneck, W_pc, W_hd, Wb_pack,
                                         Wpc_pack, Whd_pack);
  prepack_gru_kernel<<<38, 256, 0, stream>>>(Uz, Ur, Uh, Wz, Wr, Wh, bz, br,
                                             bh, gru_frags);
  embed_kernel<<<BB / 2, 256, 0, stream>>>(init_pc, init_hd, W_embed, b_embed,
                                           h0);
  gru_fast_kernel<<<BB / 8, 512, 0, stream>>>(x, h0, gru_frags, out_st,
                                              out_fs);
  heads_mfma_kernel<<<(TT * BB) / 64, 256, 0, stream>>>(
      out_st, Wb_pack, Wpc_pack, Whd_pack, b_pc, b_hd, out_hd, out_pc, out_bn);
}